// Round 4
// baseline (166.134 us; speedup 1.0000x reference)
//
#include <hip/hip_runtime.h>
#include <hip/hip_bf16.h>
#include <stdint.h>

// HybridAttention: out = (softmax(scale*QK^T) + softmax_local(scale*QK^T)) @ V
// B=4, L=2048, H=8, E=64, fp32 in/out. Local window: j in [i-2, i+1] clamped.
//
// R13: vs R12 — TWO 64-key tiles staged per barrier-phase (128 keys/phase,
// 16 phases instead of 32). Drain windows and barriers halve; 2x compute per
// drain amortizes the vmcnt(0)+barrier convoy that R9/R12's invariance
// implicates (occupancy 2x'd in R12 with zero effect => phase-locked drain,
// not occupancy, is the limiter).
// Protocol is the PROVEN synchronous one (issue -> drain -> barrier ->
// compute in the same barrier interval; NO prefetch-across-barrier, which
// failed 5x: R4/R6/R8/R10/R11).
// DMA-dest discipline: all global_load_lds dests stay < 16 KB (empirical
// boundary from this session): K tiles A,B -> DMA at [0,16K). V tiles A,B ->
// REGISTER staging (global_load_dwordx4 + ds_write_b128, byte-identical
// mapping) at [16K,32K) — plain ds_write has no dest constraint.
// Compute per tile is R12-verbatim with base offsets kb/vb.
// LDS 41 KB -> 3 blocks/CU (launch_bounds(256,3)); R12 showed occupancy is
// not the limiter in this regime.

#define LQ 2048
#define HQ 8
#define EQ 64
#define BQ 4
#define BN 64
#define RS (HQ * EQ)                      // 512 floats between seq positions
#define SCALE_LOG2E 0.18033688011112042f  // 0.125 * log2(e)
#define NTILE (LQ / BN)                   // 32 key-tiles per (b,h) in the image
#define NPHASE (NTILE / 2)                // 16 two-tile phases
#define TILE_U32 2048                     // 64x64 bf16 tile = 8 KB = 2048 u32
#define IMG_U32 (BQ * HQ * NTILE * TILE_U32)
#define BMQ 64                            // queries per block

typedef __attribute__((ext_vector_type(8))) short bf16x8;
typedef __attribute__((ext_vector_type(4))) float f32x4;
typedef __attribute__((ext_vector_type(4))) unsigned int u32x4;
typedef __attribute__((ext_vector_type(2))) unsigned int u32x2;

static __device__ __forceinline__ unsigned int f2bf(float f) {
    union { float f; unsigned int u; } c; c.f = f;
    return (c.u + 0x8000u) >> 16;
}
static __device__ __forceinline__ unsigned int pk2(float lo, float hi) {
    union { float f; unsigned int u; } a, b; a.f = lo; b.f = hi;
    return ((a.u + 0x8000u) >> 16) | ((b.u + 0x8000u) & 0xffff0000u);
}
static __device__ __forceinline__ float fexp2(float x) {
    float r;
    asm volatile("v_exp_f32 %0, %1\n\ts_nop 1" : "=v"(r) : "v"(x));
    return r;
}
static __device__ __forceinline__ void gload16(const uint32_t* g, void* l) {
    __builtin_amdgcn_global_load_lds(
        (const __attribute__((address_space(1))) unsigned int*)g,
        (__attribute__((address_space(3))) unsigned int*)l, 16, 0, 0);
}

// ---- pre-pass (R7/R9 verbatim): K -> bf16 swizzled tiles, V -> transposed
__global__ __launch_bounds__(256) void prepack_kernel(
    const float* __restrict__ K, const float* __restrict__ V,
    uint32_t* __restrict__ Kimg, uint32_t* __restrict__ Vimg)
{
    __shared__ unsigned short vt[64 * 72];  // [e][j] bf16, stride 72 (16B rows)

    const int tid = threadIdx.x;
    const int jc  = blockIdx.x;
    const int bh  = blockIdx.y;
    const int b   = bh >> 3;
    const int h   = bh & 7;
    const int j0  = jc * BN;
    const float* Kbh = K + (size_t)b * LQ * RS + h * EQ;
    const float* Vbh = V + (size_t)b * LQ * RS + h * EQ;
    uint32_t* Kt = Kimg + (size_t)(bh * NTILE + jc) * TILE_U32;
    uint32_t* Vt = Vimg + (size_t)(bh * NTILE + jc) * TILE_U32;

    #pragma unroll
    for (int it = 0; it < 2; ++it) {
        int t2 = tid + it * 256;
        int jr = t2 >> 3, eo = t2 & 7;
        const float* src = Kbh + (size_t)(j0 + jr) * RS + eo * 8;
        float4 a  = *(const float4*)src;
        float4 bv = *(const float4*)(src + 4);
        u32x4 p;
        p.x = pk2(a.x, a.y);   p.y = pk2(a.z, a.w);
        p.z = pk2(bv.x, bv.y); p.w = pk2(bv.z, bv.w);
        *(u32x4*)&Kt[jr * 32 + ((eo ^ (jr & 7)) << 2)] = p;
    }

    // V phase 1: coalesced row reads -> LDS transpose [e][j]
    {
        const int jr = tid >> 2;          // 0..63
        const int e0 = (tid & 3) * 16;    // 0,16,32,48
        const float* src = Vbh + (size_t)(j0 + jr) * RS + e0;
        #pragma unroll
        for (int q = 0; q < 4; ++q) {
            float4 a = *(const float4*)(src + q * 4);
            const int e = e0 + q * 4;
            vt[(e + 0) * 72 + jr] = (unsigned short)f2bf(a.x);
            vt[(e + 1) * 72 + jr] = (unsigned short)f2bf(a.y);
            vt[(e + 2) * 72 + jr] = (unsigned short)f2bf(a.z);
            vt[(e + 3) * 72 + jr] = (unsigned short)f2bf(a.w);
        }
    }
    __syncthreads();

    // V phase 2: contiguous LDS row reads -> coalesced swizzled global writes
    #pragma unroll
    for (int it = 0; it < 2; ++it) {
        const int i  = tid + it * 256;
        const int e  = i >> 3, jo = i & 7;
        u32x4 p = *(const u32x4*)&vt[e * 72 + jo * 8];
        *(u32x4*)&Vt[e * 32 + ((jo ^ (e & 7)) << 2)] = p;
    }
}

// ---- main attention kernel: 256 threads (4 waves), 64 queries/block,
// ---- 16 queries/wave; TWO 64-key tiles per barrier-phase (R13)
__global__ __launch_bounds__(256, 3) void hybrid_attn_v13(
    const float* __restrict__ Q, const float* __restrict__ K,
    const float* __restrict__ V, const uint32_t* __restrict__ Kimg,
    const uint32_t* __restrict__ Vimg, float* __restrict__ O)
{
    // KV layout (ushorts): K tileA [0,4096), K tileB [4096,8192)   <- DMA, bytes < 16 KB
    //                      V tileA [8192,12288), V tileB [12288,16384) <- ds_write staged
    __shared__ unsigned short KV[16384];
    __shared__ unsigned short Pt[4][1024];  // per-wave P^T: 16 q x 64 k
    __shared__ float sloc[BMQ][4];

    const int tid  = threadIdx.x;
    const int wave = tid >> 6;
    const int lane = tid & 63;
    const int c    = lane & 15;
    const int g    = lane >> 4;
    // XCD swizzle: xcd = linear_id % 8; 4 bh's per XCD per qt-slice. grid=1024.
    const int id   = blockIdx.x;            // 0..1023
    const int bh   = (id & 7) * 4 + ((id >> 3) & 3);
    const int qt   = id >> 5;               // 0..31
    const int b    = bh >> 3;
    const int h    = bh & 7;
    const int i0   = qt * BMQ;
    const int c7   = c & 7;
    const int sw3  = c7 << 1;   // Pt swizzle: bits 1-3 of the 8B-unit index

    const float* Qbh = Q + (size_t)b * LQ * RS + h * EQ;
    const float* Kbh = K + (size_t)b * LQ * RS + h * EQ;
    const float* Vbh = V + (size_t)b * LQ * RS + h * EQ;
    float*       Obh = O + (size_t)b * LQ * RS + h * EQ;

    // Q as B-operand fragments: one q-tile x 2 e-halves, scale*log2e folded in
    bf16x8 qf[2];
    {
        const int iq = i0 + wave * 16 + c;
        const float* qrow = Qbh + (size_t)iq * RS + g * 8;
        #pragma unroll
        for (int f = 0; f < 2; ++f) {
            float4 a  = *(const float4*)(qrow + f * 32);
            float4 bv = *(const float4*)(qrow + f * 32 + 4);
            union { bf16x8 v; unsigned int u[4]; } fr;
            fr.u[0] = pk2(a.x  * SCALE_LOG2E, a.y  * SCALE_LOG2E);
            fr.u[1] = pk2(a.z  * SCALE_LOG2E, a.w  * SCALE_LOG2E);
            fr.u[2] = pk2(bv.x * SCALE_LOG2E, bv.y * SCALE_LOG2E);
            fr.u[3] = pk2(bv.z * SCALE_LOG2E, bv.w * SCALE_LOG2E);
            qf[f] = fr.v;
        }
    }

    // K/V A-fragment lane offsets (ushort units) within a 16-row tile group
    const int fo0 = c * 64 + ((g ^ c7) << 3);        // k 0..31 half
    const int fo1 = c * 64 + (((4 | g) ^ c7) << 3);  // k 32..63 half

    // Pt addresses (3-bit swizzle, explicit for both write and read)
    unsigned short* pw[4];
    #pragma unroll
    for (int n = 0; n < 4; ++n)
        pw[n] = &Pt[wave][c * 64 + ((((n << 2) | g) ^ sw3) << 2)];
    unsigned short* pr0 = &Pt[wave][c * 64 + (((g << 1) ^ sw3) << 2)];
    unsigned short* pr1 = &Pt[wave][c * 64 + (((8 | (g << 1)) ^ sw3) << 2)];

    // global bases — R2-proven 4-wave x 2KB-contiguous shape per tile;
    // src/dst byte-identical for BOTH the K DMA and the V reg-staging.
    const uint32_t* kgb = Kimg + (size_t)bh * (NTILE * TILE_U32) + wave * 512 + lane * 4;
    const uint32_t* vgb = Vimg + (size_t)bh * (NTILE * TILE_U32) + wave * 512 + lane * 4;

    f32x4 oacc[4];
    #pragma unroll
    for (int eg = 0; eg < 4; ++eg) oacc[eg] = (f32x4){0.f, 0.f, 0.f, 0.f};
    float lsum = 0.f;

    for (int ph = 0; ph < NPHASE; ++ph) {
        __syncthreads();   // protect KV against previous phase's readers

        // ---- stage 2 K tiles via DMA (dests < 16 KB) + 2 V tiles via regs
        u32x4 va[2][2];
        #pragma unroll
        for (int t = 0; t < 2; ++t) {
            const size_t jt = (size_t)(ph * 2 + t) * TILE_U32;
            const uint32_t* kg = kgb + jt;
            gload16(kg,       &KV[t * 4096 + wave * 1024]);
            gload16(kg + 256, &KV[t * 4096 + wave * 1024 + 512]);
            const uint32_t* vg = vgb + jt;
            va[t][0] = *(const u32x4*)vg;
            va[t][1] = *(const u32x4*)(vg + 256);
        }
        #pragma unroll
        for (int t = 0; t < 2; ++t) {
            *(u32x4*)&KV[8192 + t * 4096 + wave * 1024 + lane * 8]       = va[t][0];
            *(u32x4*)&KV[8192 + t * 4096 + wave * 1024 + 512 + lane * 8] = va[t][1];
        }
        __syncthreads();   // barrier drains vmcnt+lgkmcnt before any wave reads

        // ---- compute both 64-key tiles (R12-verbatim per tile)
        #pragma unroll
        for (int t = 0; t < 2; ++t) {
            const int kb = t * 4096;
            const int vb = 8192 + t * 4096;

            bf16x8 kfr[4][2];
            #pragma unroll
            for (int n = 0; n < 4; ++n) {
                kfr[n][0] = *(const bf16x8*)&KV[kb + n * 1024 + fo0];
                kfr[n][1] = *(const bf16x8*)&KV[kb + n * 1024 + fo1];
            }

            f32x4 sf[4];
            #pragma unroll
            for (int n = 0; n < 4; ++n) {
                f32x4 acc = (f32x4){0.f, 0.f, 0.f, 0.f};
                acc = __builtin_amdgcn_mfma_f32_16x16x32_bf16(kfr[n][0], qf[0], acc, 0, 0, 0);
                acc = __builtin_amdgcn_mfma_f32_16x16x32_bf16(kfr[n][1], qf[1], acc, 0, 0, 0);
                sf[n] = acc;
            }
            float ls = 0.f;
            #pragma unroll
            for (int n = 0; n < 4; ++n) {
                float p0 = fexp2(sf[n][0]);
                float p1 = fexp2(sf[n][1]);
                float p2 = fexp2(sf[n][2]);
                float p3 = fexp2(sf[n][3]);
                ls += (p0 + p1) + (p2 + p3);
                u32x2 pkd;
                pkd.x = pk2(p0, p1);
                pkd.y = pk2(p2, p3);
                *(u32x2*)pw[n] = pkd;
            }
            lsum += ls;
            asm volatile("s_waitcnt lgkmcnt(0)" ::: "memory");  // wave-local Pt drain

            bf16x8 pf0 = *(const bf16x8*)pr0;
            bf16x8 pf1 = *(const bf16x8*)pr1;
            #pragma unroll
            for (int eg = 0; eg < 4; ++eg) {
                bf16x8 v0 = *(const bf16x8*)&KV[vb + eg * 1024 + fo0];
                bf16x8 v1 = *(const bf16x8*)&KV[vb + eg * 1024 + fo1];
                oacc[eg] = __builtin_amdgcn_mfma_f32_16x16x32_bf16(v0, pf0, oacc[eg], 0, 0, 0);
                oacc[eg] = __builtin_amdgcn_mfma_f32_16x16x32_bf16(v1, pf1, oacc[eg], 0, 0, 0);
            }
        }
    }

    // final row-sum reduce across the 4 quads (lanes c, c+16, c+32, c+48)
    float linv;
    {
        float l = lsum;
        l += __shfl_xor(l, 16);
        l += __shfl_xor(l, 32);
        linv = 1.0f / l;
    }

    // local branch scores: j = i-2+jj (fp32, natural-log units).
    // 256 threads cover 64 rows x 4 jj.
    {
        const int br = tid >> 2;
        const int jj = tid & 3;
        const int i  = i0 + br;
        const int j  = i - 2 + jj;
        float s = -INFINITY;
        if (j >= 0 && j < LQ) {
            const float* qrow = Qbh + (size_t)i * RS;
            const float* krow = Kbh + (size_t)j * RS;
            float acc = 0.f;
            #pragma unroll
            for (int e = 0; e < 64; e += 4) {
                float4 qa = *(const float4*)(qrow + e);
                float4 ka = *(const float4*)(krow + e);
                acc = fmaf(qa.x, ka.x, acc); acc = fmaf(qa.y, ka.y, acc);
                acc = fmaf(qa.z, ka.z, acc); acc = fmaf(qa.w, ka.w, acc);
            }
            s = 0.125f * acc;
        }
        sloc[br][jj] = s;
    }
    __syncthreads();

    // combine global + local, store (O^T: lane holds e=eg*16+g*4+r, q=c)
    {
        const int row = wave * 16 + c;
        const int i   = i0 + row;
        float s0 = sloc[row][0], s1 = sloc[row][1], s2 = sloc[row][2], s3 = sloc[row][3];
        float mx = fmaxf(fmaxf(s0, s1), fmaxf(s2, s3));
        float w0 = expf(s0 - mx), w1 = expf(s1 - mx);
        float w2 = expf(s2 - mx), w3 = expf(s3 - mx);
        float inv = 1.0f / (w0 + w1 + w2 + w3);
        w0 *= inv; w1 *= inv; w2 *= inv; w3 *= inv;
        const float li = linv;
        float* orow = Obh + (size_t)i * RS;
        #pragma unroll
        for (int eg = 0; eg < 4; ++eg) {
            const int e0 = eg * 16 + g * 4;
            float v0 = oacc[eg][0] * li;
            float v1 = oacc[eg][1] * li;
            float v2 = oacc[eg][2] * li;
            float v3 = oacc[eg][3] * li;
            if (w0 > 0.f) {
                float4 vv = *(const float4*)(Vbh + (size_t)(i - 2) * RS + e0);
                v0 = fmaf(w0, vv.x, v0); v1 = fmaf(w0, vv.y, v1);
                v2 = fmaf(w0, vv.z, v2); v3 = fmaf(w0, vv.w, v3);
            }
            if (w1 > 0.f) {
                float4 vv = *(const float4*)(Vbh + (size_t)(i - 1) * RS + e0);
                v0 = fmaf(w1, vv.x, v0); v1 = fmaf(w1, vv.y, v1);
                v2 = fmaf(w1, vv.z, v2); v3 = fmaf(w1, vv.w, v3);
            }
            {
                float4 vv = *(const float4*)(Vbh + (size_t)i * RS + e0);
                v0 = fmaf(w2, vv.x, v0); v1 = fmaf(w2, vv.y, v1);
                v2 = fmaf(w2, vv.z, v2); v3 = fmaf(w2, vv.w, v3);
            }
            if (w3 > 0.f) {
                float4 vv = *(const float4*)(Vbh + (size_t)(i + 1) * RS + e0);
                v0 = fmaf(w3, vv.x, v0); v1 = fmaf(w3, vv.y, v1);
                v2 = fmaf(w3, vv.z, v2); v3 = fmaf(w3, vv.w, v3);
            }
            float4 outv; outv.x = v0; outv.y = v1; outv.z = v2; outv.w = v3;
            *(float4*)(orow + e0) = outv;
        }
    }
}

// ---- fallback (self-contained, no workspace) ----
__global__ __launch_bounds__(256) void hybrid_attn_fb(
    const float* __restrict__ Q, const float* __restrict__ K,
    const float* __restrict__ V, float* __restrict__ O)
{
    __shared__ unsigned short Ks[64 * 64];
    __shared__ unsigned short Vt[64 * 64];
    __shared__ unsigned short Ps[4][16 * 64];
    __shared__ float sloc[64][4];

    const int tid  = threadIdx.x;
    const int wave = tid >> 6;
    const int lane = tid & 63;
    const int c    = lane & 15;
    const int g    = lane >> 4;
    const int qt   = blockIdx.x;
    const int bh   = blockIdx.y;
    const int b    = bh >> 3;
    const int h    = bh & 7;
    const int i0   = qt * 64;

    const float* Qbh = Q + (size_t)b * LQ * RS + h * EQ;
    const float* Kbh = K + (size_t)b * LQ * RS + h * EQ;
    const float* Vbh = V + (size_t)b * LQ * RS + h * EQ;
    float*       Obh = O + (size_t)b * LQ * RS + h * EQ;

    bf16x8 qf[2];
    {
        const int iA = i0 + wave * 16 + c;
        const float* qrow = Qbh + (size_t)iA * RS + g * 8;
        #pragma unroll
        for (int f = 0; f < 2; ++f) {
            float4 a  = *(const float4*)(qrow + f * 32);
            float4 bv = *(const float4*)(qrow + f * 32 + 4);
            union { bf16x8 v; unsigned int u[4]; } fr;
            fr.u[0] = pk2(a.x  * SCALE_LOG2E, a.y  * SCALE_LOG2E);
            fr.u[1] = pk2(a.z  * SCALE_LOG2E, a.w  * SCALE_LOG2E);
            fr.u[2] = pk2(bv.x * SCALE_LOG2E, bv.y * SCALE_LOG2E);
            fr.u[3] = pk2(bv.z * SCALE_LOG2E, bv.w * SCALE_LOG2E);
            qf[f] = fr.v;
        }
    }

    int kfo[4][2], vfo[4][2], pfo[2], pso[4][4];
    #pragma unroll
    for (int n = 0; n < 4; ++n)
        #pragma unroll
        for (int f = 0; f < 2; ++f)
            kfo[n][f] = (n * 16 + c) * 64 + ((((f << 2) | g) ^ (c & 7)) << 3);
    #pragma unroll
    for (int eg = 0; eg < 4; ++eg)
        #pragma unroll
        for (int kh = 0; kh < 2; ++kh)
            vfo[eg][kh] = (eg * 16 + c) * 64 + ((((kh << 2) | g) ^ (c & 7)) << 3);
    #pragma unroll
    for (int kh = 0; kh < 2; ++kh)
        pfo[kh] = c * 64 + ((((kh << 2) | g) ^ (c & 7)) << 3);
    #pragma unroll
    for (int r = 0; r < 4; ++r) {
        const int row = g * 4 + r;
        #pragma unroll
        for (int n = 0; n < 4; ++n) {
            const int col = n * 16 + c;
            pso[r][n] = row * 64 + ((((col >> 3) ^ (row & 7)) << 3) | (col & 7));
        }
    }

    f32x4 oacc[4];
    #pragma unroll
    for (int eg = 0; eg < 4; ++eg) oacc[eg] = (f32x4){0.f, 0.f, 0.f, 0.f};
    float l_r[4] = {0.f, 0.f, 0.f, 0.f};

    for (int j0 = 0; j0 < LQ; j0 += BN) {
        __syncthreads();
        #pragma unroll
        for (int it = 0; it < 2; ++it) {
            int t2 = tid + it * 256;
            int jr = t2 >> 3, eo = t2 & 7;
            const float* src = Kbh + (size_t)(j0 + jr) * RS + eo * 8;
            float4 a  = *(const float4*)src;
            float4 bv = *(const float4*)(src + 4);
            u32x4 p;
            p.x = pk2(a.x, a.y);   p.y = pk2(a.z, a.w);
            p.z = pk2(bv.x, bv.y); p.w = pk2(bv.z, bv.w);
            *(u32x4*)&Ks[jr * 64 + ((eo ^ (jr & 7)) << 3)] = p;
        }
        #pragma unroll
        for (int it = 0; it < 2; ++it) {
            int t2 = tid + it * 256;
            int e = t2 & 63, jo = t2 >> 6;
            const float* src = Vbh + (size_t)(j0 + jo * 8) * RS + e;
            float v0 = src[0 * RS], v1 = src[1 * RS], v2 = src[2 * RS], v3 = src[3 * RS];
            float v4 = src[4 * RS], v5 = src[5 * RS], v6 = src[6 * RS], v7 = src[7 * RS];
            u32x4 p;
            p.x = pk2(v0, v1); p.y = pk2(v2, v3);
            p.z = pk2(v4, v5); p.w = pk2(v6, v7);
            *(u32x4*)&Vt[e * 64 + ((jo ^ (e & 7)) << 3)] = p;
        }
        __syncthreads();

        f32x4 sf[4];
        #pragma unroll
        for (int n = 0; n < 4; ++n) {
            bf16x8 k0 = *(const bf16x8*)&Ks[kfo[n][0]];
            bf16x8 k1 = *(const bf16x8*)&Ks[kfo[n][1]];
            f32x4 acc = (f32x4){0.f, 0.f, 0.f, 0.f};
            acc = __builtin_amdgcn_mfma_f32_16x16x32_bf16(qf[0], k0, acc, 0, 0, 0);
            acc = __builtin_amdgcn_mfma_f32_16x16x32_bf16(qf[1], k1, acc, 0, 0, 0);
            sf[n] = acc;
        }
        #pragma unroll
        for (int r = 0; r < 4; ++r) {
            float p0 = fexp2(sf[0][r]);
            float p1 = fexp2(sf[1][r]);
            float p2 = fexp2(sf[2][r]);
            float p3 = fexp2(sf[3][r]);
            l_r[r] += (p0 + p1) + (p2 + p3);
            Ps[wave][pso[r][0]] = (unsigned short)f2bf(p0);
            Ps[wave][pso[r][1]] = (unsigned short)f2bf(p1);
            Ps[wave][pso[r][2]] = (unsigned short)f2bf(p2);
            Ps[wave][pso[r][3]] = (unsigned short)f2bf(p3);
        }
        asm volatile("s_waitcnt lgkmcnt(0)" ::: "memory");

        bf16x8 pf0 = *(const bf16x8*)&Ps[wave][pfo[0]];
        bf16x8 pf1 = *(const bf16x8*)&Ps[wave][pfo[1]];
        #pragma unroll
        for (int eg = 0; eg < 4; ++eg) {
            bf16x8 v0 = *(const bf16x8*)&Vt[vfo[eg][0]];
            bf16x8 v1 = *(const bf16x8*)&Vt[vfo[eg][1]];
            oacc[eg] = __builtin_amdgcn_mfma_f32_16x16x32_bf16(pf0, v0, oacc[eg], 0, 0, 0);
            oacc[eg] = __builtin_amdgcn_mfma_f32_16x16x32_bf16(pf1, v1, oacc[eg], 0, 0, 0);
        }
    }

    #pragma unroll
    for (int r = 0; r < 4; ++r) {
        float l = l_r[r];
        l += __shfl_xor(l, 1);
        l += __shfl_xor(l, 2);
        l += __shfl_xor(l, 4);
        l += __shfl_xor(l, 8);
        l_r[r] = 1.0f / l;
    }

    {
        const int br = tid >> 2;
        const int jj = tid & 3;
        const int i  = i0 + br;
        const int j  = i - 2 + jj;
        float s = -INFINITY;
        if (j >= 0 && j < LQ) {
            const float* qrow = Qbh + (size_t)i * RS;
            const float* krow = Kbh + (size_t)j * RS;
            float acc = 0.f;
            #pragma unroll
            for (int e = 0; e < 64; e += 4) {
                float4 qa = *(const float4*)(qrow + e);
                float4 ka = *(const float4*)(krow + e);
                acc = fmaf(qa.x, ka.x, acc); acc = fmaf(qa.y, ka.y, acc);
                acc = fmaf(qa.z, ka.z, acc); acc = fmaf(qa.w, ka.w, acc);
            }
            s = 0.125f * acc;
        }
        sloc[br][jj] = s;
    }
    __syncthreads();

    #pragma unroll
    for (int r = 0; r < 4; ++r) {
        const int row = wave * 16 + g * 4 + r;
        const int i   = i0 + row;
        float s0 = sloc[row][0], s1 = sloc[row][1], s2 = sloc[row][2], s3 = sloc[row][3];
        float mx = fmaxf(fmaxf(s0, s1), fmaxf(s2, s3));
        float w0 = expf(s0 - mx), w1 = expf(s1 - mx);
        float w2 = expf(s2 - mx), w3 = expf(s3 - mx);
        float inv = 1.0f / (w0 + w1 + w2 + w3);
        w0 *= inv; w1 *= inv; w2 *= inv; w3 *= inv;
        const float li = l_r[r];
        float* orow = Obh + (size_t)i * RS;
        #pragma unroll
        for (int eg = 0; eg < 4; ++eg) {
            const int e = eg * 16 + c;
            float val = oacc[eg][r] * li;
            if (w0 > 0.f) val += w0 * Vbh[(size_t)(i - 2) * RS + e];
            if (w1 > 0.f) val += w1 * Vbh[(size_t)(i - 1) * RS + e];
            if (w2 > 0.f) val += w2 * Vbh[(size_t)(i    ) * RS + e];
            if (w3 > 0.f) val += w3 * Vbh[(size_t)(i + 1) * RS + e];
            orow[e] = val;
        }
    }
}

extern "C" void kernel_launch(void* const* d_in, const int* in_sizes, int n_in,
                              void* d_out, int out_size, void* d_ws, size_t ws_size,
                              hipStream_t stream) {
    (void)in_sizes; (void)n_in; (void)out_size;
    const float* Q = (const float*)d_in[0];
    const float* K = (const float*)d_in[1];
    const float* V = (const float*)d_in[2];
    float* O = (float*)d_out;
    const size_t need = (size_t)2 * IMG_U32 * 4;  // 16 MiB
    if (ws_size >= need) {
        uint32_t* Kimg = (uint32_t*)d_ws;
        uint32_t* Vimg = Kimg + IMG_U32;
        hipLaunchKernelGGL(prepack_kernel, dim3(NTILE, BQ * HQ), dim3(256), 0, stream,
                           K, V, Kimg, Vimg);
        hipLaunchKernelGGL(hybrid_attn_v13, dim3((LQ / BMQ) * BQ * HQ), dim3(256), 0, stream,
                           Q, K, V, Kimg, Vimg, O);
    } else {
        hipLaunchKernelGGL(hybrid_attn_fb, dim3(LQ / 64, BQ * HQ), dim3(256), 0, stream,
                           Q, K, V, O);
    }
}

// Round 5
// 156.150 us; speedup vs baseline: 1.0639x; 1.0639x over previous
//
#include <hip/hip_runtime.h>
#include <hip/hip_bf16.h>
#include <stdint.h>

// HybridAttention: out = (softmax(scale*QK^T) + softmax_local(scale*QK^T)) @ V
// B=4, L=2048, H=8, E=64, fp32 in/out. Local window: j in [i-2, i+1] clamped.
//
// R14: (a) attn kernel = R12 VERBATIM (79.4 us, passed, absmax 0.0156) —
// R13's fused-window experiment regressed (+9 us) and is reverted.
// (b) prepack V-path rewritten vector-only, conflict-free, OUTPUT BYTES
// IDENTICAL. Evidence: bench total minus attn dur is a stable ~76 us
// constant across R0/R12/R13 => prepack (never profiled, never optimized)
// is the suspected dominant remainder. Old V phase1 did 16 scalar
// ds_write_u16/thread, 8-way bank-conflicted (stride-72: all four e0
// groups alias mod 32). New design:
//   phase1: raw fp32 rows -> ds_write_b128 into [64][64] fp32 LDS with
//           per-row chunk swizzle p=(ec&8)|((ec^s)&7), s(j)=(j&7)^(j>>3).
//           Writes hit the 1KB/instr floor exactly (derived conflict-free).
//   phase2: column gather (2-way = free), pk2 pack (same rounding as f2bf),
//           coalesced u32x4 stores to the SAME swizzled Vt positions.
// K path and all formats unchanged.

#define LQ 2048
#define HQ 8
#define EQ 64
#define BQ 4
#define BN 64
#define RS (HQ * EQ)                      // 512 floats between seq positions
#define SCALE_LOG2E 0.18033688011112042f  // 0.125 * log2(e)
#define NTILE (LQ / BN)                   // 32 key-tiles per (b,h)
#define TILE_U32 2048                     // 64x64 bf16 tile = 8 KB = 2048 u32
#define IMG_U32 (BQ * HQ * NTILE * TILE_U32)
#define BMQ 64                            // queries per block

typedef __attribute__((ext_vector_type(8))) short bf16x8;
typedef __attribute__((ext_vector_type(4))) float f32x4;
typedef __attribute__((ext_vector_type(4))) unsigned int u32x4;
typedef __attribute__((ext_vector_type(2))) unsigned int u32x2;

static __device__ __forceinline__ unsigned int f2bf(float f) {
    union { float f; unsigned int u; } c; c.f = f;
    return (c.u + 0x8000u) >> 16;
}
static __device__ __forceinline__ unsigned int pk2(float lo, float hi) {
    union { float f; unsigned int u; } a, b; a.f = lo; b.f = hi;
    return ((a.u + 0x8000u) >> 16) | ((b.u + 0x8000u) & 0xffff0000u);
}
static __device__ __forceinline__ float fexp2(float x) {
    float r;
    asm volatile("v_exp_f32 %0, %1\n\ts_nop 1" : "=v"(r) : "v"(x));
    return r;
}
static __device__ __forceinline__ void gload16(const uint32_t* g, void* l) {
    __builtin_amdgcn_global_load_lds(
        (const __attribute__((address_space(1))) unsigned int*)g,
        (__attribute__((address_space(3))) unsigned int*)l, 16, 0, 0);
}

// ---- pre-pass v2: K path verbatim; V path vectorized conflict-free.
// Output images are byte-identical to the R7/R9/R12 prepack.
__global__ __launch_bounds__(256) void prepack_kernel(
    const float* __restrict__ K, const float* __restrict__ V,
    uint32_t* __restrict__ Kimg, uint32_t* __restrict__ Vimg)
{
    __shared__ float vf[64 * 64];  // [j][chunk-swizzled e] fp32, 16 KB

    const int tid = threadIdx.x;
    const int jc  = blockIdx.x;
    const int bh  = blockIdx.y;
    const int b   = bh >> 3;
    const int h   = bh & 7;
    const int j0  = jc * BN;
    const float* Kbh = K + (size_t)b * LQ * RS + h * EQ;
    const float* Vbh = V + (size_t)b * LQ * RS + h * EQ;
    uint32_t* Kt = Kimg + (size_t)(bh * NTILE + jc) * TILE_U32;
    uint32_t* Vt = Vimg + (size_t)(bh * NTILE + jc) * TILE_U32;

    // K: coalesced fp32 reads -> pk2 -> coalesced swizzled u32x4 stores
    #pragma unroll
    for (int it = 0; it < 2; ++it) {
        int t2 = tid + it * 256;
        int jr = t2 >> 3, eo = t2 & 7;
        const float* src = Kbh + (size_t)(j0 + jr) * RS + eo * 8;
        float4 a  = *(const float4*)src;
        float4 bv = *(const float4*)(src + 4);
        u32x4 p;
        p.x = pk2(a.x, a.y);   p.y = pk2(a.z, a.w);
        p.z = pk2(bv.x, bv.y); p.w = pk2(bv.z, bv.w);
        *(u32x4*)&Kt[jr * 32 + ((eo ^ (jr & 7)) << 2)] = p;
    }

    // V phase 1: coalesced row reads -> swizzled fp32 LDS, all ds_write_b128.
    // Row j stores e-chunk ec (4 floats) at position p=(ec&8)|((ec^s)&7),
    // s(j) = (j&7)^(j>>3). Bijective per row; write banks at the b128 floor.
    {
        const int jr = tid >> 2;               // 0..63
        const int s  = (jr & 7) ^ (jr >> 3);   // row swizzle constant
        const float* src = Vbh + (size_t)(j0 + jr) * RS + (tid & 3) * 16;
        #pragma unroll
        for (int q = 0; q < 4; ++q) {
            float4 a = *(const float4*)(src + q * 4);
            const int ec = (tid & 3) * 4 + q;  // e-chunk 0..15
            const int p  = (ec & 8) | ((ec ^ s) & 7);
            *(float4*)&vf[jr * 64 + p * 4] = a;
        }
    }
    __syncthreads();

    // V phase 2: column gather (conflict-free: bank = ((ec^k^jo'^e)&7)*4+(e&3),
    // 2 lanes/bank), pk2 pairs, coalesced stores to the same swizzled slots.
    #pragma unroll
    for (int it = 0; it < 2; ++it) {
        const int u   = tid + it * 256;
        const int e   = u >> 3;             // 0..63
        const int jop = u & 7;              // stored (output) chunk position
        const int jo  = jop ^ (e & 7);      // source j-chunk (XOR self-inverse)
        const int ec  = e >> 2;
        float v[8];
        #pragma unroll
        for (int k = 0; k < 8; ++k) {
            const int j = jo * 8 + k;
            const int p = (ec & 8) | ((ec ^ (j & 7) ^ (j >> 3)) & 7);
            v[k] = vf[j * 64 + p * 4 + (e & 3)];
        }
        u32x4 pq;
        pq.x = pk2(v[0], v[1]); pq.y = pk2(v[2], v[3]);
        pq.z = pk2(v[4], v[5]); pq.w = pk2(v[6], v[7]);
        *(u32x4*)&Vt[e * 32 + (jop << 2)] = pq;
    }
}

// ---- main attention kernel: R12 VERBATIM (4 waves, 64 queries/block,
// ---- 16 queries/wave; one chunk per barrier; proven 79.4 us)
__global__ __launch_bounds__(256, 4) void hybrid_attn_v14(
    const float* __restrict__ Q, const float* __restrict__ K,
    const float* __restrict__ V, const uint32_t* __restrict__ Kimg,
    const uint32_t* __restrict__ Vimg, float* __restrict__ O)
{
    __shared__ unsigned short KV[8192];     // Ks [0,4096), Vt [4096,8192) ushorts
    __shared__ unsigned short Pt[4][1024];  // per-wave P^T: 16 q x 64 k
    __shared__ float sloc[BMQ][4];

    const int tid  = threadIdx.x;
    const int wave = tid >> 6;
    const int lane = tid & 63;
    const int c    = lane & 15;
    const int g    = lane >> 4;
    // XCD swizzle: xcd = linear_id % 8; 4 bh's per XCD per qt-slice. grid=1024.
    const int id   = blockIdx.x;            // 0..1023
    const int bh   = (id & 7) * 4 + ((id >> 3) & 3);
    const int qt   = id >> 5;               // 0..31
    const int b    = bh >> 3;
    const int h    = bh & 7;
    const int i0   = qt * BMQ;
    const int c7   = c & 7;
    const int sw3  = c7 << 1;   // Pt swizzle: bits 1-3 of the 8B-unit index

    const float* Qbh = Q + (size_t)b * LQ * RS + h * EQ;
    const float* Kbh = K + (size_t)b * LQ * RS + h * EQ;
    const float* Vbh = V + (size_t)b * LQ * RS + h * EQ;
    float*       Obh = O + (size_t)b * LQ * RS + h * EQ;

    // Q as B-operand fragments: one q-tile x 2 e-halves, scale*log2e folded in
    bf16x8 qf[2];
    {
        const int iq = i0 + wave * 16 + c;
        const float* qrow = Qbh + (size_t)iq * RS + g * 8;
        #pragma unroll
        for (int f = 0; f < 2; ++f) {
            float4 a  = *(const float4*)(qrow + f * 32);
            float4 bv = *(const float4*)(qrow + f * 32 + 4);
            union { bf16x8 v; unsigned int u[4]; } fr;
            fr.u[0] = pk2(a.x  * SCALE_LOG2E, a.y  * SCALE_LOG2E);
            fr.u[1] = pk2(a.z  * SCALE_LOG2E, a.w  * SCALE_LOG2E);
            fr.u[2] = pk2(bv.x * SCALE_LOG2E, bv.y * SCALE_LOG2E);
            fr.u[3] = pk2(bv.z * SCALE_LOG2E, bv.w * SCALE_LOG2E);
            qf[f] = fr.v;
        }
    }

    // K/V A-fragment lane offsets (ushort units) within a 16-row tile group
    const int fo0 = c * 64 + ((g ^ c7) << 3);        // k 0..31 half
    const int fo1 = c * 64 + (((4 | g) ^ c7) << 3);  // k 32..63 half

    // Pt addresses (3-bit swizzle, explicit for both write and read)
    unsigned short* pw[4];
    #pragma unroll
    for (int n = 0; n < 4; ++n)
        pw[n] = &Pt[wave][c * 64 + ((((n << 2) | g) ^ sw3) << 2)];
    unsigned short* pr0 = &Pt[wave][c * 64 + (((g << 1) ^ sw3) << 2)];
    unsigned short* pr1 = &Pt[wave][c * 64 + (((8 | (g << 1)) ^ sw3) << 2)];

    // global DMA bases — R2-proven 4-wave x 2KB-contiguous shape:
    // wave w stages tile bytes [w*2048, w*2048+2048) in 2 loads of 1 KB;
    // src/dst byte-identical. All LDS dests < 16 KB.
    const uint32_t* kgb = Kimg + (size_t)bh * (NTILE * TILE_U32) + wave * 512 + lane * 4;
    const uint32_t* vgb = Vimg + (size_t)bh * (NTILE * TILE_U32) + wave * 512 + lane * 4;

    f32x4 oacc[4];
    #pragma unroll
    for (int eg = 0; eg < 4; ++eg) oacc[eg] = (f32x4){0.f, 0.f, 0.f, 0.f};
    float lsum = 0.f;

    for (int jc = 0; jc < NTILE; ++jc) {
        __syncthreads();   // protect KV against previous iteration's readers
        const uint32_t* kg = kgb + (size_t)jc * TILE_U32;
        const uint32_t* vg = vgb + (size_t)jc * TILE_U32;
        gload16(kg,       &KV[wave * 1024]);
        gload16(kg + 256, &KV[wave * 1024 + 512]);
        gload16(vg,       &KV[4096 + wave * 1024]);
        gload16(vg + 256, &KV[4096 + wave * 1024 + 512]);
        __syncthreads();   // barrier drains vmcnt before any wave proceeds

        // K A-fragments
        bf16x8 kfr[4][2];
        #pragma unroll
        for (int n = 0; n < 4; ++n) {
            kfr[n][0] = *(const bf16x8*)&KV[n * 1024 + fo0];
            kfr[n][1] = *(const bf16x8*)&KV[n * 1024 + fo1];
        }

        // S^T = K*Q^T, p = exp2(s), pack, 4x ds_write_b64
        f32x4 sf[4];
        #pragma unroll
        for (int n = 0; n < 4; ++n) {
            f32x4 acc = (f32x4){0.f, 0.f, 0.f, 0.f};
            acc = __builtin_amdgcn_mfma_f32_16x16x32_bf16(kfr[n][0], qf[0], acc, 0, 0, 0);
            acc = __builtin_amdgcn_mfma_f32_16x16x32_bf16(kfr[n][1], qf[1], acc, 0, 0, 0);
            sf[n] = acc;
        }
        float ls = 0.f;
        #pragma unroll
        for (int n = 0; n < 4; ++n) {
            float p0 = fexp2(sf[n][0]);
            float p1 = fexp2(sf[n][1]);
            float p2 = fexp2(sf[n][2]);
            float p3 = fexp2(sf[n][3]);
            ls += (p0 + p1) + (p2 + p3);
            u32x2 pkd;
            pkd.x = pk2(p0, p1);
            pkd.y = pk2(p2, p3);
            *(u32x2*)pw[n] = pkd;
        }
        lsum += ls;
        asm volatile("s_waitcnt lgkmcnt(0)" ::: "memory");  // wave-local Pt drain

        // P B-fragments + V A-fragments -> O^T accumulate
        bf16x8 pf0 = *(const bf16x8*)pr0;
        bf16x8 pf1 = *(const bf16x8*)pr1;
        #pragma unroll
        for (int eg = 0; eg < 4; ++eg) {
            bf16x8 v0 = *(const bf16x8*)&KV[4096 + eg * 1024 + fo0];
            bf16x8 v1 = *(const bf16x8*)&KV[4096 + eg * 1024 + fo1];
            oacc[eg] = __builtin_amdgcn_mfma_f32_16x16x32_bf16(v0, pf0, oacc[eg], 0, 0, 0);
            oacc[eg] = __builtin_amdgcn_mfma_f32_16x16x32_bf16(v1, pf1, oacc[eg], 0, 0, 0);
        }
    }

    // final row-sum reduce across the 4 quads (lanes c, c+16, c+32, c+48)
    float linv;
    {
        float l = lsum;
        l += __shfl_xor(l, 16);
        l += __shfl_xor(l, 32);
        linv = 1.0f / l;
    }

    // local branch scores: j = i-2+jj (fp32, natural-log units).
    // 256 threads cover 64 rows x 4 jj.
    {
        const int br = tid >> 2;
        const int jj = tid & 3;
        const int i  = i0 + br;
        const int j  = i - 2 + jj;
        float s = -INFINITY;
        if (j >= 0 && j < LQ) {
            const float* qrow = Qbh + (size_t)i * RS;
            const float* krow = Kbh + (size_t)j * RS;
            float acc = 0.f;
            #pragma unroll
            for (int e = 0; e < 64; e += 4) {
                float4 qa = *(const float4*)(qrow + e);
                float4 ka = *(const float4*)(krow + e);
                acc = fmaf(qa.x, ka.x, acc); acc = fmaf(qa.y, ka.y, acc);
                acc = fmaf(qa.z, ka.z, acc); acc = fmaf(qa.w, ka.w, acc);
            }
            s = 0.125f * acc;
        }
        sloc[br][jj] = s;
    }
    __syncthreads();

    // combine global + local, store (O^T: lane holds e=eg*16+g*4+r, q=c)
    {
        const int row = wave * 16 + c;
        const int i   = i0 + row;
        float s0 = sloc[row][0], s1 = sloc[row][1], s2 = sloc[row][2], s3 = sloc[row][3];
        float mx = fmaxf(fmaxf(s0, s1), fmaxf(s2, s3));
        float w0 = expf(s0 - mx), w1 = expf(s1 - mx);
        float w2 = expf(s2 - mx), w3 = expf(s3 - mx);
        float inv = 1.0f / (w0 + w1 + w2 + w3);
        w0 *= inv; w1 *= inv; w2 *= inv; w3 *= inv;
        const float li = linv;
        float* orow = Obh + (size_t)i * RS;
        #pragma unroll
        for (int eg = 0; eg < 4; ++eg) {
            const int e0 = eg * 16 + g * 4;
            float v0 = oacc[eg][0] * li;
            float v1 = oacc[eg][1] * li;
            float v2 = oacc[eg][2] * li;
            float v3 = oacc[eg][3] * li;
            if (w0 > 0.f) {
                float4 vv = *(const float4*)(Vbh + (size_t)(i - 2) * RS + e0);
                v0 = fmaf(w0, vv.x, v0); v1 = fmaf(w0, vv.y, v1);
                v2 = fmaf(w0, vv.z, v2); v3 = fmaf(w0, vv.w, v3);
            }
            if (w1 > 0.f) {
                float4 vv = *(const float4*)(Vbh + (size_t)(i - 1) * RS + e0);
                v0 = fmaf(w1, vv.x, v0); v1 = fmaf(w1, vv.y, v1);
                v2 = fmaf(w1, vv.z, v2); v3 = fmaf(w1, vv.w, v3);
            }
            {
                float4 vv = *(const float4*)(Vbh + (size_t)i * RS + e0);
                v0 = fmaf(w2, vv.x, v0); v1 = fmaf(w2, vv.y, v1);
                v2 = fmaf(w2, vv.z, v2); v3 = fmaf(w2, vv.w, v3);
            }
            if (w3 > 0.f) {
                float4 vv = *(const float4*)(Vbh + (size_t)(i + 1) * RS + e0);
                v0 = fmaf(w3, vv.x, v0); v1 = fmaf(w3, vv.y, v1);
                v2 = fmaf(w3, vv.z, v2); v3 = fmaf(w3, vv.w, v3);
            }
            float4 outv; outv.x = v0; outv.y = v1; outv.z = v2; outv.w = v3;
            *(float4*)(orow + e0) = outv;
        }
    }
}

// ---- fallback (self-contained, no workspace) ----
__global__ __launch_bounds__(256) void hybrid_attn_fb(
    const float* __restrict__ Q, const float* __restrict__ K,
    const float* __restrict__ V, float* __restrict__ O)
{
    __shared__ unsigned short Ks[64 * 64];
    __shared__ unsigned short Vt[64 * 64];
    __shared__ unsigned short Ps[4][16 * 64];
    __shared__ float sloc[64][4];

    const int tid  = threadIdx.x;
    const int wave = tid >> 6;
    const int lane = tid & 63;
    const int c    = lane & 15;
    const int g    = lane >> 4;
    const int qt   = blockIdx.x;
    const int bh   = blockIdx.y;
    const int b    = bh >> 3;
    const int h    = bh & 7;
    const int i0   = qt * 64;

    const float* Qbh = Q + (size_t)b * LQ * RS + h * EQ;
    const float* Kbh = K + (size_t)b * LQ * RS + h * EQ;
    const float* Vbh = V + (size_t)b * LQ * RS + h * EQ;
    float*       Obh = O + (size_t)b * LQ * RS + h * EQ;

    bf16x8 qf[2];
    {
        const int iA = i0 + wave * 16 + c;
        const float* qrow = Qbh + (size_t)iA * RS + g * 8;
        #pragma unroll
        for (int f = 0; f < 2; ++f) {
            float4 a  = *(const float4*)(qrow + f * 32);
            float4 bv = *(const float4*)(qrow + f * 32 + 4);
            union { bf16x8 v; unsigned int u[4]; } fr;
            fr.u[0] = pk2(a.x  * SCALE_LOG2E, a.y  * SCALE_LOG2E);
            fr.u[1] = pk2(a.z  * SCALE_LOG2E, a.w  * SCALE_LOG2E);
            fr.u[2] = pk2(bv.x * SCALE_LOG2E, bv.y * SCALE_LOG2E);
            fr.u[3] = pk2(bv.z * SCALE_LOG2E, bv.w * SCALE_LOG2E);
            qf[f] = fr.v;
        }
    }

    int kfo[4][2], vfo[4][2], pfo[2], pso[4][4];
    #pragma unroll
    for (int n = 0; n < 4; ++n)
        #pragma unroll
        for (int f = 0; f < 2; ++f)
            kfo[n][f] = (n * 16 + c) * 64 + ((((f << 2) | g) ^ (c & 7)) << 3);
    #pragma unroll
    for (int eg = 0; eg < 4; ++eg)
        #pragma unroll
        for (int kh = 0; kh < 2; ++kh)
            vfo[eg][kh] = (eg * 16 + c) * 64 + ((((kh << 2) | g) ^ (c & 7)) << 3);
    #pragma unroll
    for (int kh = 0; kh < 2; ++kh)
        pfo[kh] = c * 64 + ((((kh << 2) | g) ^ (c & 7)) << 3);
    #pragma unroll
    for (int r = 0; r < 4; ++r) {
        const int row = g * 4 + r;
        #pragma unroll
        for (int n = 0; n < 4; ++n) {
            const int col = n * 16 + c;
            pso[r][n] = row * 64 + ((((col >> 3) ^ (row & 7)) << 3) | (col & 7));
        }
    }

    f32x4 oacc[4];
    #pragma unroll
    for (int eg = 0; eg < 4; ++eg) oacc[eg] = (f32x4){0.f, 0.f, 0.f, 0.f};
    float l_r[4] = {0.f, 0.f, 0.f, 0.f};

    for (int j0 = 0; j0 < LQ; j0 += BN) {
        __syncthreads();
        #pragma unroll
        for (int it = 0; it < 2; ++it) {
            int t2 = tid + it * 256;
            int jr = t2 >> 3, eo = t2 & 7;
            const float* src = Kbh + (size_t)(j0 + jr) * RS + eo * 8;
            float4 a  = *(const float4*)src;
            float4 bv = *(const float4*)(src + 4);
            u32x4 p;
            p.x = pk2(a.x, a.y);   p.y = pk2(a.z, a.w);
            p.z = pk2(bv.x, bv.y); p.w = pk2(bv.z, bv.w);
            *(u32x4*)&Ks[jr * 64 + ((eo ^ (jr & 7)) << 3)] = p;
        }
        #pragma unroll
        for (int it = 0; it < 2; ++it) {
            int t2 = tid + it * 256;
            int e = t2 & 63, jo = t2 >> 6;
            const float* src = Vbh + (size_t)(j0 + jo * 8) * RS + e;
            float v0 = src[0 * RS], v1 = src[1 * RS], v2 = src[2 * RS], v3 = src[3 * RS];
            float v4 = src[4 * RS], v5 = src[5 * RS], v6 = src[6 * RS], v7 = src[7 * RS];
            u32x4 p;
            p.x = pk2(v0, v1); p.y = pk2(v2, v3);
            p.z = pk2(v4, v5); p.w = pk2(v6, v7);
            *(u32x4*)&Vt[e * 64 + ((jo ^ (e & 7)) << 3)] = p;
        }
        __syncthreads();

        f32x4 sf[4];
        #pragma unroll
        for (int n = 0; n < 4; ++n) {
            bf16x8 k0 = *(const bf16x8*)&Ks[kfo[n][0]];
            bf16x8 k1 = *(const bf16x8*)&Ks[kfo[n][1]];
            f32x4 acc = (f32x4){0.f, 0.f, 0.f, 0.f};
            acc = __builtin_amdgcn_mfma_f32_16x16x32_bf16(qf[0], k0, acc, 0, 0, 0);
            acc = __builtin_amdgcn_mfma_f32_16x16x32_bf16(qf[1], k1, acc, 0, 0, 0);
            sf[n] = acc;
        }
        #pragma unroll
        for (int r = 0; r < 4; ++r) {
            float p0 = fexp2(sf[0][r]);
            float p1 = fexp2(sf[1][r]);
            float p2 = fexp2(sf[2][r]);
            float p3 = fexp2(sf[3][r]);
            l_r[r] += (p0 + p1) + (p2 + p3);
            Ps[wave][pso[r][0]] = (unsigned short)f2bf(p0);
            Ps[wave][pso[r][1]] = (unsigned short)f2bf(p1);
            Ps[wave][pso[r][2]] = (unsigned short)f2bf(p2);
            Ps[wave][pso[r][3]] = (unsigned short)f2bf(p3);
        }
        asm volatile("s_waitcnt lgkmcnt(0)" ::: "memory");

        bf16x8 pf0 = *(const bf16x8*)&Ps[wave][pfo[0]];
        bf16x8 pf1 = *(const bf16x8*)&Ps[wave][pfo[1]];
        #pragma unroll
        for (int eg = 0; eg < 4; ++eg) {
            bf16x8 v0 = *(const bf16x8*)&Vt[vfo[eg][0]];
            bf16x8 v1 = *(const bf16x8*)&Vt[vfo[eg][1]];
            oacc[eg] = __builtin_amdgcn_mfma_f32_16x16x32_bf16(pf0, v0, oacc[eg], 0, 0, 0);
            oacc[eg] = __builtin_amdgcn_mfma_f32_16x16x32_bf16(pf1, v1, oacc[eg], 0, 0, 0);
        }
    }

    #pragma unroll
    for (int r = 0; r < 4; ++r) {
        float l = l_r[r];
        l += __shfl_xor(l, 1);
        l += __shfl_xor(l, 2);
        l += __shfl_xor(l, 4);
        l += __shfl_xor(l, 8);
        l_r[r] = 1.0f / l;
    }

    {
        const int br = tid >> 2;
        const int jj = tid & 3;
        const int i  = i0 + br;
        const int j  = i - 2 + jj;
        float s = -INFINITY;
        if (j >= 0 && j < LQ) {
            const float* qrow = Qbh + (size_t)i * RS;
            const float* krow = Kbh + (size_t)j * RS;
            float acc = 0.f;
            #pragma unroll
            for (int e = 0; e < 64; e += 4) {
                float4 qa = *(const float4*)(qrow + e);
                float4 ka = *(const float4*)(krow + e);
                acc = fmaf(qa.x, ka.x, acc); acc = fmaf(qa.y, ka.y, acc);
                acc = fmaf(qa.z, ka.z, acc); acc = fmaf(qa.w, ka.w, acc);
            }
            s = 0.125f * acc;
        }
        sloc[br][jj] = s;
    }
    __syncthreads();

    #pragma unroll
    for (int r = 0; r < 4; ++r) {
        const int row = wave * 16 + g * 4 + r;
        const int i   = i0 + row;
        float s0 = sloc[row][0], s1 = sloc[row][1], s2 = sloc[row][2], s3 = sloc[row][3];
        float mx = fmaxf(fmaxf(s0, s1), fmaxf(s2, s3));
        float w0 = expf(s0 - mx), w1 = expf(s1 - mx);
        float w2 = expf(s2 - mx), w3 = expf(s3 - mx);
        float inv = 1.0f / (w0 + w1 + w2 + w3);
        w0 *= inv; w1 *= inv; w2 *= inv; w3 *= inv;
        const float li = l_r[r];
        float* orow = Obh + (size_t)i * RS;
        #pragma unroll
        for (int eg = 0; eg < 4; ++eg) {
            const int e = eg * 16 + c;
            float val = oacc[eg][r] * li;
            if (w0 > 0.f) val += w0 * Vbh[(size_t)(i - 2) * RS + e];
            if (w1 > 0.f) val += w1 * Vbh[(size_t)(i - 1) * RS + e];
            if (w2 > 0.f) val += w2 * Vbh[(size_t)(i    ) * RS + e];
            if (w3 > 0.f) val += w3 * Vbh[(size_t)(i + 1) * RS + e];
            orow[e] = val;
        }
    }
}

extern "C" void kernel_launch(void* const* d_in, const int* in_sizes, int n_in,
                              void* d_out, int out_size, void* d_ws, size_t ws_size,
                              hipStream_t stream) {
    (void)in_sizes; (void)n_in; (void)out_size;
    const float* Q = (const float*)d_in[0];
    const float* K = (const float*)d_in[1];
    const float* V = (const float*)d_in[2];
    float* O = (float*)d_out;
    const size_t need = (size_t)2 * IMG_U32 * 4;  // 16 MiB
    if (ws_size >= need) {
        uint32_t* Kimg = (uint32_t*)d_ws;
        uint32_t* Vimg = Kimg + IMG_U32;
        hipLaunchKernelGGL(prepack_kernel, dim3(NTILE, BQ * HQ), dim3(256), 0, stream,
                           K, V, Kimg, Vimg);
        hipLaunchKernelGGL(hybrid_attn_v14, dim3((LQ / BMQ) * BQ * HQ), dim3(256), 0, stream,
                           Q, K, V, Kimg, Vimg, O);
    } else {
        hipLaunchKernelGGL(hybrid_attn_fb, dim3(LQ / 64, BQ * HQ), dim3(256), 0, stream,
                           Q, K, V, O);
    }
}

// Round 6
// 154.070 us; speedup vs baseline: 1.0783x; 1.0135x over previous
//
#include <hip/hip_runtime.h>
#include <hip/hip_bf16.h>
#include <stdint.h>

// HybridAttention: out = (softmax(scale*QK^T) + softmax_local(scale*QK^T)) @ V
// B=4, L=2048, H=8, E=64, fp32 in/out. Local window: j in [i-2, i+1] clamped.
//
// R15: ONE variable vs R12/R14 — staging switched from global_load_lds (DMA)
// to REGISTER staging with one-iteration-ahead global->reg prefetch (T14
// async-STAGE split). Evidence: per-iter wall (~6000 cyc) is invariant to
// occupancy (R12), per-wave compute (R9), and window count (R13) => the
// in-window DMA issue+drain latency is the serial chain. Reg prefetch takes
// it off the critical path:
//   prologue: load tile0 -> regs
//   loop: barrier; ds_write regs->LDS (byte-identical layout, conflict-free);
//         load tile jc+1 -> regs (flies across compute); barrier; compute.
// SAFETY vs the 5 failed DMA-prefetch variants (R4/R6/R8/R10/R11): registers
// are wave-private, so the cross-barrier prefetch has NO LDS hazard; LDS is
// written only synchronously inside the window and drained by the barrier.
// Compute/epilogue/LDS layout: R12-verbatim. Prepack: R14 v2 (kept).

#define LQ 2048
#define HQ 8
#define EQ 64
#define BQ 4
#define BN 64
#define RS (HQ * EQ)                      // 512 floats between seq positions
#define SCALE_LOG2E 0.18033688011112042f  // 0.125 * log2(e)
#define NTILE (LQ / BN)                   // 32 key-tiles per (b,h)
#define TILE_U32 2048                     // 64x64 bf16 tile = 8 KB = 2048 u32
#define IMG_U32 (BQ * HQ * NTILE * TILE_U32)
#define BMQ 64                            // queries per block

typedef __attribute__((ext_vector_type(8))) short bf16x8;
typedef __attribute__((ext_vector_type(4))) float f32x4;
typedef __attribute__((ext_vector_type(4))) unsigned int u32x4;
typedef __attribute__((ext_vector_type(2))) unsigned int u32x2;

static __device__ __forceinline__ unsigned int f2bf(float f) {
    union { float f; unsigned int u; } c; c.f = f;
    return (c.u + 0x8000u) >> 16;
}
static __device__ __forceinline__ unsigned int pk2(float lo, float hi) {
    union { float f; unsigned int u; } a, b; a.f = lo; b.f = hi;
    return ((a.u + 0x8000u) >> 16) | ((b.u + 0x8000u) & 0xffff0000u);
}
static __device__ __forceinline__ float fexp2(float x) {
    float r;
    asm volatile("v_exp_f32 %0, %1\n\ts_nop 1" : "=v"(r) : "v"(x));
    return r;
}

// ---- pre-pass v2 (R14): K path verbatim; V path vectorized conflict-free.
// Output images byte-identical to the R7/R9/R12 prepack.
__global__ __launch_bounds__(256) void prepack_kernel(
    const float* __restrict__ K, const float* __restrict__ V,
    uint32_t* __restrict__ Kimg, uint32_t* __restrict__ Vimg)
{
    __shared__ float vf[64 * 64];  // [j][chunk-swizzled e] fp32, 16 KB

    const int tid = threadIdx.x;
    const int jc  = blockIdx.x;
    const int bh  = blockIdx.y;
    const int b   = bh >> 3;
    const int h   = bh & 7;
    const int j0  = jc * BN;
    const float* Kbh = K + (size_t)b * LQ * RS + h * EQ;
    const float* Vbh = V + (size_t)b * LQ * RS + h * EQ;
    uint32_t* Kt = Kimg + (size_t)(bh * NTILE + jc) * TILE_U32;
    uint32_t* Vt = Vimg + (size_t)(bh * NTILE + jc) * TILE_U32;

    // K: coalesced fp32 reads -> pk2 -> coalesced swizzled u32x4 stores
    #pragma unroll
    for (int it = 0; it < 2; ++it) {
        int t2 = tid + it * 256;
        int jr = t2 >> 3, eo = t2 & 7;
        const float* src = Kbh + (size_t)(j0 + jr) * RS + eo * 8;
        float4 a  = *(const float4*)src;
        float4 bv = *(const float4*)(src + 4);
        u32x4 p;
        p.x = pk2(a.x, a.y);   p.y = pk2(a.z, a.w);
        p.z = pk2(bv.x, bv.y); p.w = pk2(bv.z, bv.w);
        *(u32x4*)&Kt[jr * 32 + ((eo ^ (jr & 7)) << 2)] = p;
    }

    // V phase 1: coalesced row reads -> swizzled fp32 LDS, all ds_write_b128.
    {
        const int jr = tid >> 2;               // 0..63
        const int s  = (jr & 7) ^ (jr >> 3);   // row swizzle constant
        const float* src = Vbh + (size_t)(j0 + jr) * RS + (tid & 3) * 16;
        #pragma unroll
        for (int q = 0; q < 4; ++q) {
            float4 a = *(const float4*)(src + q * 4);
            const int ec = (tid & 3) * 4 + q;  // e-chunk 0..15
            const int p  = (ec & 8) | ((ec ^ s) & 7);
            *(float4*)&vf[jr * 64 + p * 4] = a;
        }
    }
    __syncthreads();

    // V phase 2: column gather (2-way = free), pk2 pairs, coalesced stores.
    #pragma unroll
    for (int it = 0; it < 2; ++it) {
        const int u   = tid + it * 256;
        const int e   = u >> 3;             // 0..63
        const int jop = u & 7;              // stored (output) chunk position
        const int jo  = jop ^ (e & 7);      // source j-chunk (XOR self-inverse)
        const int ec  = e >> 2;
        float v[8];
        #pragma unroll
        for (int k = 0; k < 8; ++k) {
            const int j = jo * 8 + k;
            const int p = (ec & 8) | ((ec ^ (j & 7) ^ (j >> 3)) & 7);
            v[k] = vf[j * 64 + p * 4 + (e & 3)];
        }
        u32x4 pq;
        pq.x = pk2(v[0], v[1]); pq.y = pk2(v[2], v[3]);
        pq.z = pk2(v[4], v[5]); pq.w = pk2(v[6], v[7]);
        *(u32x4*)&Vt[e * 32 + (jop << 2)] = pq;
    }
}

// ---- main attention kernel: 4 waves, 64 queries/block, 16 queries/wave;
// ---- reg-staged LDS with one-iter-ahead global->reg prefetch (R15)
__global__ __launch_bounds__(256, 4) void hybrid_attn_v15(
    const float* __restrict__ Q, const float* __restrict__ K,
    const float* __restrict__ V, const uint32_t* __restrict__ Kimg,
    const uint32_t* __restrict__ Vimg, float* __restrict__ O)
{
    __shared__ unsigned short KV[8192];     // Ks [0,4096), Vt [4096,8192) ushorts
    __shared__ unsigned short Pt[4][1024];  // per-wave P^T: 16 q x 64 k
    __shared__ float sloc[BMQ][4];

    const int tid  = threadIdx.x;
    const int wave = tid >> 6;
    const int lane = tid & 63;
    const int c    = lane & 15;
    const int g    = lane >> 4;
    // XCD swizzle: xcd = linear_id % 8; 4 bh's per XCD per qt-slice. grid=1024.
    const int id   = blockIdx.x;            // 0..1023
    const int bh   = (id & 7) * 4 + ((id >> 3) & 3);
    const int qt   = id >> 5;               // 0..31
    const int b    = bh >> 3;
    const int h    = bh & 7;
    const int i0   = qt * BMQ;
    const int c7   = c & 7;
    const int sw3  = c7 << 1;   // Pt swizzle: bits 1-3 of the 8B-unit index

    const float* Qbh = Q + (size_t)b * LQ * RS + h * EQ;
    const float* Kbh = K + (size_t)b * LQ * RS + h * EQ;
    const float* Vbh = V + (size_t)b * LQ * RS + h * EQ;
    float*       Obh = O + (size_t)b * LQ * RS + h * EQ;

    // Q as B-operand fragments: one q-tile x 2 e-halves, scale*log2e folded in
    bf16x8 qf[2];
    {
        const int iq = i0 + wave * 16 + c;
        const float* qrow = Qbh + (size_t)iq * RS + g * 8;
        #pragma unroll
        for (int f = 0; f < 2; ++f) {
            float4 a  = *(const float4*)(qrow + f * 32);
            float4 bv = *(const float4*)(qrow + f * 32 + 4);
            union { bf16x8 v; unsigned int u[4]; } fr;
            fr.u[0] = pk2(a.x  * SCALE_LOG2E, a.y  * SCALE_LOG2E);
            fr.u[1] = pk2(a.z  * SCALE_LOG2E, a.w  * SCALE_LOG2E);
            fr.u[2] = pk2(bv.x * SCALE_LOG2E, bv.y * SCALE_LOG2E);
            fr.u[3] = pk2(bv.z * SCALE_LOG2E, bv.w * SCALE_LOG2E);
            qf[f] = fr.v;
        }
    }

    // K/V A-fragment lane offsets (ushort units) within a 16-row tile group
    const int fo0 = c * 64 + ((g ^ c7) << 3);        // k 0..31 half
    const int fo1 = c * 64 + (((4 | g) ^ c7) << 3);  // k 32..63 half

    // Pt addresses (3-bit swizzle, explicit for both write and read)
    unsigned short* pw[4];
    #pragma unroll
    for (int n = 0; n < 4; ++n)
        pw[n] = &Pt[wave][c * 64 + ((((n << 2) | g) ^ sw3) << 2)];
    unsigned short* pr0 = &Pt[wave][c * 64 + (((g << 1) ^ sw3) << 2)];
    unsigned short* pr1 = &Pt[wave][c * 64 + (((8 | (g << 1)) ^ sw3) << 2)];

    // global per-lane source bases — same 4-wave x 2KB-contiguous shape as
    // R12's DMA; dst ds_write addresses are byte-identical (lane*16B).
    const uint32_t* kgb = Kimg + (size_t)bh * (NTILE * TILE_U32) + wave * 512 + lane * 4;
    const uint32_t* vgb = Vimg + (size_t)bh * (NTILE * TILE_U32) + wave * 512 + lane * 4;

    // LDS dest pointers (ushort units; lane*8 ushorts = 16B per lane)
    unsigned short* kd0 = &KV[wave * 1024 + lane * 8];
    unsigned short* kd1 = &KV[wave * 1024 + 512 + lane * 8];
    unsigned short* vd0 = &KV[4096 + wave * 1024 + lane * 8];
    unsigned short* vd1 = &KV[4096 + wave * 1024 + 512 + lane * 8];

    f32x4 oacc[4];
    #pragma unroll
    for (int eg = 0; eg < 4; ++eg) oacc[eg] = (f32x4){0.f, 0.f, 0.f, 0.f};
    float lsum = 0.f;

    // prologue: load tile 0 into registers (wave-private; no LDS hazard)
    u32x4 kr0 = *(const u32x4*)kgb;
    u32x4 kr1 = *(const u32x4*)(kgb + 256);
    u32x4 vr0 = *(const u32x4*)vgb;
    u32x4 vr1 = *(const u32x4*)(vgb + 256);

    for (int jc = 0; jc < NTILE; ++jc) {
        __syncthreads();   // previous iteration's KV readers are done
        // regs -> LDS (compiler inserts the vmcnt for the loads, which were
        // issued one full compute-phase ago => near-zero wait)
        *(u32x4*)kd0 = kr0;
        *(u32x4*)kd1 = kr1;
        *(u32x4*)vd0 = vr0;
        *(u32x4*)vd1 = vr1;
        // prefetch tile jc+1 into regs; flies across the whole compute phase
        if (jc + 1 < NTILE) {
            const uint32_t* kg = kgb + (size_t)(jc + 1) * TILE_U32;
            const uint32_t* vg = vgb + (size_t)(jc + 1) * TILE_U32;
            kr0 = *(const u32x4*)kg;
            kr1 = *(const u32x4*)(kg + 256);
            vr0 = *(const u32x4*)vg;
            vr1 = *(const u32x4*)(vg + 256);
        }
        __syncthreads();   // staged tile visible to all waves (drains lgkm)

        // K A-fragments
        bf16x8 kfr[4][2];
        #pragma unroll
        for (int n = 0; n < 4; ++n) {
            kfr[n][0] = *(const bf16x8*)&KV[n * 1024 + fo0];
            kfr[n][1] = *(const bf16x8*)&KV[n * 1024 + fo1];
        }

        // S^T = K*Q^T, p = exp2(s), pack, 4x ds_write_b64
        f32x4 sf[4];
        #pragma unroll
        for (int n = 0; n < 4; ++n) {
            f32x4 acc = (f32x4){0.f, 0.f, 0.f, 0.f};
            acc = __builtin_amdgcn_mfma_f32_16x16x32_bf16(kfr[n][0], qf[0], acc, 0, 0, 0);
            acc = __builtin_amdgcn_mfma_f32_16x16x32_bf16(kfr[n][1], qf[1], acc, 0, 0, 0);
            sf[n] = acc;
        }
        float ls = 0.f;
        #pragma unroll
        for (int n = 0; n < 4; ++n) {
            float p0 = fexp2(sf[n][0]);
            float p1 = fexp2(sf[n][1]);
            float p2 = fexp2(sf[n][2]);
            float p3 = fexp2(sf[n][3]);
            ls += (p0 + p1) + (p2 + p3);
            u32x2 pkd;
            pkd.x = pk2(p0, p1);
            pkd.y = pk2(p2, p3);
            *(u32x2*)pw[n] = pkd;
        }
        lsum += ls;
        asm volatile("s_waitcnt lgkmcnt(0)" ::: "memory");  // wave-local Pt drain

        // P B-fragments + V A-fragments -> O^T accumulate
        bf16x8 pf0 = *(const bf16x8*)pr0;
        bf16x8 pf1 = *(const bf16x8*)pr1;
        #pragma unroll
        for (int eg = 0; eg < 4; ++eg) {
            bf16x8 v0 = *(const bf16x8*)&KV[4096 + eg * 1024 + fo0];
            bf16x8 v1 = *(const bf16x8*)&KV[4096 + eg * 1024 + fo1];
            oacc[eg] = __builtin_amdgcn_mfma_f32_16x16x32_bf16(v0, pf0, oacc[eg], 0, 0, 0);
            oacc[eg] = __builtin_amdgcn_mfma_f32_16x16x32_bf16(v1, pf1, oacc[eg], 0, 0, 0);
        }
    }

    // final row-sum reduce across the 4 quads (lanes c, c+16, c+32, c+48)
    float linv;
    {
        float l = lsum;
        l += __shfl_xor(l, 16);
        l += __shfl_xor(l, 32);
        linv = 1.0f / l;
    }

    // local branch scores: j = i-2+jj (fp32, natural-log units).
    {
        const int br = tid >> 2;
        const int jj = tid & 3;
        const int i  = i0 + br;
        const int j  = i - 2 + jj;
        float s = -INFINITY;
        if (j >= 0 && j < LQ) {
            const float* qrow = Qbh + (size_t)i * RS;
            const float* krow = Kbh + (size_t)j * RS;
            float acc = 0.f;
            #pragma unroll
            for (int e = 0; e < 64; e += 4) {
                float4 qa = *(const float4*)(qrow + e);
                float4 ka = *(const float4*)(krow + e);
                acc = fmaf(qa.x, ka.x, acc); acc = fmaf(qa.y, ka.y, acc);
                acc = fmaf(qa.z, ka.z, acc); acc = fmaf(qa.w, ka.w, acc);
            }
            s = 0.125f * acc;
        }
        sloc[br][jj] = s;
    }
    __syncthreads();

    // combine global + local, store (O^T: lane holds e=eg*16+g*4+r, q=c)
    {
        const int row = wave * 16 + c;
        const int i   = i0 + row;
        float s0 = sloc[row][0], s1 = sloc[row][1], s2 = sloc[row][2], s3 = sloc[row][3];
        float mx = fmaxf(fmaxf(s0, s1), fmaxf(s2, s3));
        float w0 = expf(s0 - mx), w1 = expf(s1 - mx);
        float w2 = expf(s2 - mx), w3 = expf(s3 - mx);
        float inv = 1.0f / (w0 + w1 + w2 + w3);
        w0 *= inv; w1 *= inv; w2 *= inv; w3 *= inv;
        const float li = linv;
        float* orow = Obh + (size_t)i * RS;
        #pragma unroll
        for (int eg = 0; eg < 4; ++eg) {
            const int e0 = eg * 16 + g * 4;
            float v0 = oacc[eg][0] * li;
            float v1 = oacc[eg][1] * li;
            float v2 = oacc[eg][2] * li;
            float v3 = oacc[eg][3] * li;
            if (w0 > 0.f) {
                float4 vv = *(const float4*)(Vbh + (size_t)(i - 2) * RS + e0);
                v0 = fmaf(w0, vv.x, v0); v1 = fmaf(w0, vv.y, v1);
                v2 = fmaf(w0, vv.z, v2); v3 = fmaf(w0, vv.w, v3);
            }
            if (w1 > 0.f) {
                float4 vv = *(const float4*)(Vbh + (size_t)(i - 1) * RS + e0);
                v0 = fmaf(w1, vv.x, v0); v1 = fmaf(w1, vv.y, v1);
                v2 = fmaf(w1, vv.z, v2); v3 = fmaf(w1, vv.w, v3);
            }
            {
                float4 vv = *(const float4*)(Vbh + (size_t)i * RS + e0);
                v0 = fmaf(w2, vv.x, v0); v1 = fmaf(w2, vv.y, v1);
                v2 = fmaf(w2, vv.z, v2); v3 = fmaf(w2, vv.w, v3);
            }
            if (w3 > 0.f) {
                float4 vv = *(const float4*)(Vbh + (size_t)(i + 1) * RS + e0);
                v0 = fmaf(w3, vv.x, v0); v1 = fmaf(w3, vv.y, v1);
                v2 = fmaf(w3, vv.z, v2); v3 = fmaf(w3, vv.w, v3);
            }
            float4 outv; outv.x = v0; outv.y = v1; outv.z = v2; outv.w = v3;
            *(float4*)(orow + e0) = outv;
        }
    }
}

// ---- fallback (self-contained, no workspace) ----
__global__ __launch_bounds__(256) void hybrid_attn_fb(
    const float* __restrict__ Q, const float* __restrict__ K,
    const float* __restrict__ V, float* __restrict__ O)
{
    __shared__ unsigned short Ks[64 * 64];
    __shared__ unsigned short Vt[64 * 64];
    __shared__ unsigned short Ps[4][16 * 64];
    __shared__ float sloc[64][4];

    const int tid  = threadIdx.x;
    const int wave = tid >> 6;
    const int lane = tid & 63;
    const int c    = lane & 15;
    const int g    = lane >> 4;
    const int qt   = blockIdx.x;
    const int bh   = blockIdx.y;
    const int b    = bh >> 3;
    const int h    = bh & 7;
    const int i0   = qt * 64;

    const float* Qbh = Q + (size_t)b * LQ * RS + h * EQ;
    const float* Kbh = K + (size_t)b * LQ * RS + h * EQ;
    const float* Vbh = V + (size_t)b * LQ * RS + h * EQ;
    float*       Obh = O + (size_t)b * LQ * RS + h * EQ;

    bf16x8 qf[2];
    {
        const int iA = i0 + wave * 16 + c;
        const float* qrow = Qbh + (size_t)iA * RS + g * 8;
        #pragma unroll
        for (int f = 0; f < 2; ++f) {
            float4 a  = *(const float4*)(qrow + f * 32);
            float4 bv = *(const float4*)(qrow + f * 32 + 4);
            union { bf16x8 v; unsigned int u[4]; } fr;
            fr.u[0] = pk2(a.x  * SCALE_LOG2E, a.y  * SCALE_LOG2E);
            fr.u[1] = pk2(a.z  * SCALE_LOG2E, a.w  * SCALE_LOG2E);
            fr.u[2] = pk2(bv.x * SCALE_LOG2E, bv.y * SCALE_LOG2E);
            fr.u[3] = pk2(bv.z * SCALE_LOG2E, bv.w * SCALE_LOG2E);
            qf[f] = fr.v;
        }
    }

    int kfo[4][2], vfo[4][2], pfo[2], pso[4][4];
    #pragma unroll
    for (int n = 0; n < 4; ++n)
        #pragma unroll
        for (int f = 0; f < 2; ++f)
            kfo[n][f] = (n * 16 + c) * 64 + ((((f << 2) | g) ^ (c & 7)) << 3);
    #pragma unroll
    for (int eg = 0; eg < 4; ++eg)
        #pragma unroll
        for (int kh = 0; kh < 2; ++kh)
            vfo[eg][kh] = (eg * 16 + c) * 64 + ((((kh << 2) | g) ^ (c & 7)) << 3);
    #pragma unroll
    for (int kh = 0; kh < 2; ++kh)
        pfo[kh] = c * 64 + ((((kh << 2) | g) ^ (c & 7)) << 3);
    #pragma unroll
    for (int r = 0; r < 4; ++r) {
        const int row = g * 4 + r;
        #pragma unroll
        for (int n = 0; n < 4; ++n) {
            const int col = n * 16 + c;
            pso[r][n] = row * 64 + ((((col >> 3) ^ (row & 7)) << 3) | (col & 7));
        }
    }

    f32x4 oacc[4];
    #pragma unroll
    for (int eg = 0; eg < 4; ++eg) oacc[eg] = (f32x4){0.f, 0.f, 0.f, 0.f};
    float l_r[4] = {0.f, 0.f, 0.f, 0.f};

    for (int j0 = 0; j0 < LQ; j0 += BN) {
        __syncthreads();
        #pragma unroll
        for (int it = 0; it < 2; ++it) {
            int t2 = tid + it * 256;
            int jr = t2 >> 3, eo = t2 & 7;
            const float* src = Kbh + (size_t)(j0 + jr) * RS + eo * 8;
            float4 a  = *(const float4*)src;
            float4 bv = *(const float4*)(src + 4);
            u32x4 p;
            p.x = pk2(a.x, a.y);   p.y = pk2(a.z, a.w);
            p.z = pk2(bv.x, bv.y); p.w = pk2(bv.z, bv.w);
            *(u32x4*)&Ks[jr * 64 + ((eo ^ (jr & 7)) << 3)] = p;
        }
        #pragma unroll
        for (int it = 0; it < 2; ++it) {
            int t2 = tid + it * 256;
            int e = t2 & 63, jo = t2 >> 6;
            const float* src = Vbh + (size_t)(j0 + jo * 8) * RS + e;
            float v0 = src[0 * RS], v1 = src[1 * RS], v2 = src[2 * RS], v3 = src[3 * RS];
            float v4 = src[4 * RS], v5 = src[5 * RS], v6 = src[6 * RS], v7 = src[7 * RS];
            u32x4 p;
            p.x = pk2(v0, v1); p.y = pk2(v2, v3);
            p.z = pk2(v4, v5); p.w = pk2(v6, v7);
            *(u32x4*)&Vt[e * 64 + ((jo ^ (e & 7)) << 3)] = p;
        }
        __syncthreads();

        f32x4 sf[4];
        #pragma unroll
        for (int n = 0; n < 4; ++n) {
            bf16x8 k0 = *(const bf16x8*)&Ks[kfo[n][0]];
            bf16x8 k1 = *(const bf16x8*)&Ks[kfo[n][1]];
            f32x4 acc = (f32x4){0.f, 0.f, 0.f, 0.f};
            acc = __builtin_amdgcn_mfma_f32_16x16x32_bf16(qf[0], k0, acc, 0, 0, 0);
            acc = __builtin_amdgcn_mfma_f32_16x16x32_bf16(qf[1], k1, acc, 0, 0, 0);
            sf[n] = acc;
        }
        #pragma unroll
        for (int r = 0; r < 4; ++r) {
            float p0 = fexp2(sf[0][r]);
            float p1 = fexp2(sf[1][r]);
            float p2 = fexp2(sf[2][r]);
            float p3 = fexp2(sf[3][r]);
            l_r[r] += (p0 + p1) + (p2 + p3);
            Ps[wave][pso[r][0]] = (unsigned short)f2bf(p0);
            Ps[wave][pso[r][1]] = (unsigned short)f2bf(p1);
            Ps[wave][pso[r][2]] = (unsigned short)f2bf(p2);
            Ps[wave][pso[r][3]] = (unsigned short)f2bf(p3);
        }
        asm volatile("s_waitcnt lgkmcnt(0)" ::: "memory");

        bf16x8 pf0 = *(const bf16x8*)&Ps[wave][pfo[0]];
        bf16x8 pf1 = *(const bf16x8*)&Ps[wave][pfo[1]];
        #pragma unroll
        for (int eg = 0; eg < 4; ++eg) {
            bf16x8 v0 = *(const bf16x8*)&Vt[vfo[eg][0]];
            bf16x8 v1 = *(const bf16x8*)&Vt[vfo[eg][1]];
            oacc[eg] = __builtin_amdgcn_mfma_f32_16x16x32_bf16(pf0, v0, oacc[eg], 0, 0, 0);
            oacc[eg] = __builtin_amdgcn_mfma_f32_16x16x32_bf16(pf1, v1, oacc[eg], 0, 0, 0);
        }
    }

    #pragma unroll
    for (int r = 0; r < 4; ++r) {
        float l = l_r[r];
        l += __shfl_xor(l, 1);
        l += __shfl_xor(l, 2);
        l += __shfl_xor(l, 4);
        l += __shfl_xor(l, 8);
        l_r[r] = 1.0f / l;
    }

    {
        const int br = tid >> 2;
        const int jj = tid & 3;
        const int i  = i0 + br;
        const int j  = i - 2 + jj;
        float s = -INFINITY;
        if (j >= 0 && j < LQ) {
            const float* qrow = Qbh + (size_t)i * RS;
            const float* krow = Kbh + (size_t)j * RS;
            float acc = 0.f;
            #pragma unroll
            for (int e = 0; e < 64; e += 4) {
                float4 qa = *(const float4*)(qrow + e);
                float4 ka = *(const float4*)(krow + e);
                acc = fmaf(qa.x, ka.x, acc); acc = fmaf(qa.y, ka.y, acc);
                acc = fmaf(qa.z, ka.z, acc); acc = fmaf(qa.w, ka.w, acc);
            }
            s = 0.125f * acc;
        }
        sloc[br][jj] = s;
    }
    __syncthreads();

    #pragma unroll
    for (int r = 0; r < 4; ++r) {
        const int row = wave * 16 + g * 4 + r;
        const int i   = i0 + row;
        float s0 = sloc[row][0], s1 = sloc[row][1], s2 = sloc[row][2], s3 = sloc[row][3];
        float mx = fmaxf(fmaxf(s0, s1), fmaxf(s2, s3));
        float w0 = expf(s0 - mx), w1 = expf(s1 - mx);
        float w2 = expf(s2 - mx), w3 = expf(s3 - mx);
        float inv = 1.0f / (w0 + w1 + w2 + w3);
        w0 *= inv; w1 *= inv; w2 *= inv; w3 *= inv;
        const float li = l_r[r];
        float* orow = Obh + (size_t)i * RS;
        #pragma unroll
        for (int eg = 0; eg < 4; ++eg) {
            const int e = eg * 16 + c;
            float val = oacc[eg][r] * li;
            if (w0 > 0.f) val += w0 * Vbh[(size_t)(i - 2) * RS + e];
            if (w1 > 0.f) val += w1 * Vbh[(size_t)(i - 1) * RS + e];
            if (w2 > 0.f) val += w2 * Vbh[(size_t)(i    ) * RS + e];
            if (w3 > 0.f) val += w3 * Vbh[(size_t)(i + 1) * RS + e];
            orow[e] = val;
        }
    }
}

extern "C" void kernel_launch(void* const* d_in, const int* in_sizes, int n_in,
                              void* d_out, int out_size, void* d_ws, size_t ws_size,
                              hipStream_t stream) {
    (void)in_sizes; (void)n_in; (void)out_size;
    const float* Q = (const float*)d_in[0];
    const float* K = (const float*)d_in[1];
    const float* V = (const float*)d_in[2];
    float* O = (float*)d_out;
    const size_t need = (size_t)2 * IMG_U32 * 4;  // 16 MiB
    if (ws_size >= need) {
        uint32_t* Kimg = (uint32_t*)d_ws;
        uint32_t* Vimg = Kimg + IMG_U32;
        hipLaunchKernelGGL(prepack_kernel, dim3(NTILE, BQ * HQ), dim3(256), 0, stream,
                           K, V, Kimg, Vimg);
        hipLaunchKernelGGL(hybrid_attn_v15, dim3((LQ / BMQ) * BQ * HQ), dim3(256), 0, stream,
                           Q, K, V, Kimg, Vimg, O);
    } else {
        hipLaunchKernelGGL(hybrid_attn_fb, dim3(LQ / 64, BQ * HQ), dim3(256), 0, stream,
                           Q, K, V, O);
    }
}

// Round 7
// 148.732 us; speedup vs baseline: 1.1170x; 1.0359x over previous
//
#include <hip/hip_runtime.h>
#include <hip/hip_bf16.h>
#include <stdint.h>

// HybridAttention: out = (softmax(scale*QK^T) + softmax_local(scale*QK^T)) @ V
// B=4, L=2048, H=8, E=64, fp32 in/out. Local window: j in [i-2, i+1] clamped.
//
// R16: vs R15 — the P LDS round-trip (4x ds_write_b64 + lgkmcnt(0) drain +
// 2x ds_read_b128, ~300 serial cycles/iter + pipe traffic) is ELIMINATED.
// Mechanism: the PV B-fragment needs lane (g,c) to hold P at k=8g+j /
// 32+8g+j (HW-fixed). By remapping which KEY each QK^T MFMA row reads —
// key(n,m) = 8*(m>>2)+(m&3)+{0,4,32,36}[n] — lane (g,c)'s QK^T outputs are
// exactly those 16 values. P packs in-register (pk2 -> 2x bf16x8) straight
// into PV. Zero cross-lane movement, Pt deleted, mid-compute drain deleted
// (V reads can now hoist/overlap).
// Induced change: prepack K position = eo ^ ((jr&3)|(((jr>>3)&1)<<2)) with
// lane-constant read swizzle ss=(c&3)|(((c>>2)&1)<<2) — keeps the K-frag
// reads at the conflict-free bank minimum under the remapped rows (verified:
// store/read compose to identity; 32 lanes on chunks 0-3, 32 on 4-7).
// Staging: R15's reg-prefetch (kept verbatim). V path: unchanged.

#define LQ 2048
#define HQ 8
#define EQ 64
#define BQ 4
#define BN 64
#define RS (HQ * EQ)                      // 512 floats between seq positions
#define SCALE_LOG2E 0.18033688011112042f  // 0.125 * log2(e)
#define NTILE (LQ / BN)                   // 32 key-tiles per (b,h)
#define TILE_U32 2048                     // 64x64 bf16 tile = 8 KB = 2048 u32
#define IMG_U32 (BQ * HQ * NTILE * TILE_U32)
#define BMQ 64                            // queries per block

typedef __attribute__((ext_vector_type(8))) short bf16x8;
typedef __attribute__((ext_vector_type(4))) float f32x4;
typedef __attribute__((ext_vector_type(4))) unsigned int u32x4;
typedef __attribute__((ext_vector_type(2))) unsigned int u32x2;

static __device__ __forceinline__ unsigned int f2bf(float f) {
    union { float f; unsigned int u; } c; c.f = f;
    return (c.u + 0x8000u) >> 16;
}
static __device__ __forceinline__ unsigned int pk2(float lo, float hi) {
    union { float f; unsigned int u; } a, b; a.f = lo; b.f = hi;
    return ((a.u + 0x8000u) >> 16) | ((b.u + 0x8000u) & 0xffff0000u);
}
static __device__ __forceinline__ float fexp2(float x) {
    float r;
    asm volatile("v_exp_f32 %0, %1\n\ts_nop 1" : "=v"(r) : "v"(x));
    return r;
}

// ---- pre-pass v3: K position swizzle adapted to the R16 remapped reads
// (eo ^ ((jr&3)|bit3)); V path = R14's vectorized conflict-free version.
__global__ __launch_bounds__(256) void prepack_kernel(
    const float* __restrict__ K, const float* __restrict__ V,
    uint32_t* __restrict__ Kimg, uint32_t* __restrict__ Vimg)
{
    __shared__ float vf[64 * 64];  // [j][chunk-swizzled e] fp32, 16 KB

    const int tid = threadIdx.x;
    const int jc  = blockIdx.x;
    const int bh  = blockIdx.y;
    const int b   = bh >> 3;
    const int h   = bh & 7;
    const int j0  = jc * BN;
    const float* Kbh = K + (size_t)b * LQ * RS + h * EQ;
    const float* Vbh = V + (size_t)b * LQ * RS + h * EQ;
    uint32_t* Kt = Kimg + (size_t)(bh * NTILE + jc) * TILE_U32;
    uint32_t* Vt = Vimg + (size_t)(bh * NTILE + jc) * TILE_U32;

    // K: coalesced fp32 reads -> pk2 -> swizzled u32x4 stores.
    // Position = eo ^ s(jr), s(jr) = (jr&3) | (((jr>>3)&1)<<2)  [R16]
    #pragma unroll
    for (int it = 0; it < 2; ++it) {
        int t2 = tid + it * 256;
        int jr = t2 >> 3, eo = t2 & 7;
        const float* src = Kbh + (size_t)(j0 + jr) * RS + eo * 8;
        float4 a  = *(const float4*)src;
        float4 bv = *(const float4*)(src + 4);
        u32x4 p;
        p.x = pk2(a.x, a.y);   p.y = pk2(a.z, a.w);
        p.z = pk2(bv.x, bv.y); p.w = pk2(bv.z, bv.w);
        const int s = (jr & 3) | (((jr >> 3) & 1) << 2);
        *(u32x4*)&Kt[jr * 32 + ((eo ^ s) << 2)] = p;
    }

    // V phase 1: coalesced row reads -> swizzled fp32 LDS, all ds_write_b128.
    {
        const int jr = tid >> 2;               // 0..63
        const int s  = (jr & 7) ^ (jr >> 3);   // row swizzle constant
        const float* src = Vbh + (size_t)(j0 + jr) * RS + (tid & 3) * 16;
        #pragma unroll
        for (int q = 0; q < 4; ++q) {
            float4 a = *(const float4*)(src + q * 4);
            const int ec = (tid & 3) * 4 + q;  // e-chunk 0..15
            const int p  = (ec & 8) | ((ec ^ s) & 7);
            *(float4*)&vf[jr * 64 + p * 4] = a;
        }
    }
    __syncthreads();

    // V phase 2: column gather (2-way = free), pk2 pairs, coalesced stores.
    #pragma unroll
    for (int it = 0; it < 2; ++it) {
        const int u   = tid + it * 256;
        const int e   = u >> 3;             // 0..63
        const int jop = u & 7;              // stored (output) chunk position
        const int jo  = jop ^ (e & 7);      // source j-chunk (XOR self-inverse)
        const int ec  = e >> 2;
        float v[8];
        #pragma unroll
        for (int k = 0; k < 8; ++k) {
            const int j = jo * 8 + k;
            const int p = (ec & 8) | ((ec ^ (j & 7) ^ (j >> 3)) & 7);
            v[k] = vf[j * 64 + p * 4 + (e & 3)];
        }
        u32x4 pq;
        pq.x = pk2(v[0], v[1]); pq.y = pk2(v[2], v[3]);
        pq.z = pk2(v[4], v[5]); pq.w = pk2(v[6], v[7]);
        *(u32x4*)&Vt[e * 32 + (jop << 2)] = pq;
    }
}

// ---- main attention kernel: 4 waves, 64 queries/block, 16 queries/wave;
// ---- reg-prefetch staging (R15) + in-register P path (R16)
__global__ __launch_bounds__(256, 4) void hybrid_attn_v16(
    const float* __restrict__ Q, const float* __restrict__ K,
    const float* __restrict__ V, const uint32_t* __restrict__ Kimg,
    const uint32_t* __restrict__ Vimg, float* __restrict__ O)
{
    __shared__ unsigned short KV[8192];     // Ks [0,4096), Vt [4096,8192) ushorts
    __shared__ float sloc[BMQ][4];

    const int tid  = threadIdx.x;
    const int wave = tid >> 6;
    const int lane = tid & 63;
    const int c    = lane & 15;
    const int g    = lane >> 4;
    // XCD swizzle: xcd = linear_id % 8; 4 bh's per XCD per qt-slice. grid=1024.
    const int id   = blockIdx.x;            // 0..1023
    const int bh   = (id & 7) * 4 + ((id >> 3) & 3);
    const int qt   = id >> 5;               // 0..31
    const int b    = bh >> 3;
    const int h    = bh & 7;
    const int i0   = qt * BMQ;
    const int c7   = c & 7;

    const float* Qbh = Q + (size_t)b * LQ * RS + h * EQ;
    const float* Kbh = K + (size_t)b * LQ * RS + h * EQ;
    const float* Vbh = V + (size_t)b * LQ * RS + h * EQ;
    float*       Obh = O + (size_t)b * LQ * RS + h * EQ;

    // Q as B-operand fragments: one q-tile x 2 e-halves, scale*log2e folded in
    bf16x8 qf[2];
    {
        const int iq = i0 + wave * 16 + c;
        const float* qrow = Qbh + (size_t)iq * RS + g * 8;
        #pragma unroll
        for (int f = 0; f < 2; ++f) {
            float4 a  = *(const float4*)(qrow + f * 32);
            float4 bv = *(const float4*)(qrow + f * 32 + 4);
            union { bf16x8 v; unsigned int u[4]; } fr;
            fr.u[0] = pk2(a.x  * SCALE_LOG2E, a.y  * SCALE_LOG2E);
            fr.u[1] = pk2(a.z  * SCALE_LOG2E, a.w  * SCALE_LOG2E);
            fr.u[2] = pk2(bv.x * SCALE_LOG2E, bv.y * SCALE_LOG2E);
            fr.u[3] = pk2(bv.z * SCALE_LOG2E, bv.w * SCALE_LOG2E);
            qf[f] = fr.v;
        }
    }

    // R16 K-fragment addressing: MFMA n, A-row m reads key
    //   key(n,m) = 8*(m>>2) + (m&3) + {0,4,32,36}[n]
    // so lane (g,c)'s QK^T outputs are exactly its PV B-fragment P values.
    const int rb = ((c >> 2) << 3) + (c & 3);
    const int ss = (c & 3) | (((c >> 2) & 1) << 2);  // lane-constant K swizzle
    int kfo[4][2];
    #pragma unroll
    for (int n = 0; n < 4; ++n) {
        const int off = ((n & 1) << 2) + ((n >> 1) << 5);  // 0,4,32,36
        const int r   = rb + off;
        kfo[n][0] = r * 64 + ((g       ^ ss) << 3);
        kfo[n][1] = r * 64 + (((4 | g) ^ ss) << 3);
    }
    // V A-fragment lane offsets (unchanged layout: row = eg*16+c, row&7 = c7)
    const int vo0 = c * 64 + ((g ^ c7) << 3);        // k 0..31 half
    const int vo1 = c * 64 + (((4 | g) ^ c7) << 3);  // k 32..63 half

    // global per-lane source bases — 4-wave x 2KB-contiguous shape (R2-proven)
    const uint32_t* kgb = Kimg + (size_t)bh * (NTILE * TILE_U32) + wave * 512 + lane * 4;
    const uint32_t* vgb = Vimg + (size_t)bh * (NTILE * TILE_U32) + wave * 512 + lane * 4;

    // LDS dest pointers (ushort units; lane*8 ushorts = 16B per lane)
    unsigned short* kd0 = &KV[wave * 1024 + lane * 8];
    unsigned short* kd1 = &KV[wave * 1024 + 512 + lane * 8];
    unsigned short* vd0 = &KV[4096 + wave * 1024 + lane * 8];
    unsigned short* vd1 = &KV[4096 + wave * 1024 + 512 + lane * 8];

    f32x4 oacc[4];
    #pragma unroll
    for (int eg = 0; eg < 4; ++eg) oacc[eg] = (f32x4){0.f, 0.f, 0.f, 0.f};
    float lsum = 0.f;

    // prologue: load tile 0 into registers (wave-private; no LDS hazard)
    u32x4 kr0 = *(const u32x4*)kgb;
    u32x4 kr1 = *(const u32x4*)(kgb + 256);
    u32x4 vr0 = *(const u32x4*)vgb;
    u32x4 vr1 = *(const u32x4*)(vgb + 256);

    for (int jc = 0; jc < NTILE; ++jc) {
        __syncthreads();   // previous iteration's KV readers are done
        *(u32x4*)kd0 = kr0;
        *(u32x4*)kd1 = kr1;
        *(u32x4*)vd0 = vr0;
        *(u32x4*)vd1 = vr1;
        // prefetch tile jc+1 into regs; flies across the whole compute phase
        if (jc + 1 < NTILE) {
            const uint32_t* kg = kgb + (size_t)(jc + 1) * TILE_U32;
            const uint32_t* vg = vgb + (size_t)(jc + 1) * TILE_U32;
            kr0 = *(const u32x4*)kg;
            kr1 = *(const u32x4*)(kg + 256);
            vr0 = *(const u32x4*)vg;
            vr1 = *(const u32x4*)(vg + 256);
        }
        __syncthreads();   // staged tile visible to all waves

        // K A-fragments (remapped rows)
        bf16x8 kfr[4][2];
        #pragma unroll
        for (int n = 0; n < 4; ++n) {
            kfr[n][0] = *(const bf16x8*)&KV[kfo[n][0]];
            kfr[n][1] = *(const bf16x8*)&KV[kfo[n][1]];
        }

        // S^T = K*Q^T; sf[n][r] = S[q=c][k = 8g + r + {0,4,32,36}[n]]
        f32x4 sf[4];
        #pragma unroll
        for (int n = 0; n < 4; ++n) {
            f32x4 acc = (f32x4){0.f, 0.f, 0.f, 0.f};
            acc = __builtin_amdgcn_mfma_f32_16x16x32_bf16(kfr[n][0], qf[0], acc, 0, 0, 0);
            acc = __builtin_amdgcn_mfma_f32_16x16x32_bf16(kfr[n][1], qf[1], acc, 0, 0, 0);
            sf[n] = acc;
        }

        // p = exp2(s); pack IN REGISTER into the PV B-fragments.
        // P0 covers k=8g..8g+7 (n=0,1); P1 covers k=32+8g..+7 (n=2,3).
        union { bf16x8 v; unsigned int u[4]; } P0, P1;
        float ls = 0.f;
        #pragma unroll
        for (int n = 0; n < 4; ++n) {
            float p0 = fexp2(sf[n][0]);
            float p1 = fexp2(sf[n][1]);
            float p2 = fexp2(sf[n][2]);
            float p3 = fexp2(sf[n][3]);
            ls += (p0 + p1) + (p2 + p3);
            const unsigned int lo = pk2(p0, p1);
            const unsigned int hi = pk2(p2, p3);
            if (n == 0)      { P0.u[0] = lo; P0.u[1] = hi; }
            else if (n == 1) { P0.u[2] = lo; P0.u[3] = hi; }
            else if (n == 2) { P1.u[0] = lo; P1.u[1] = hi; }
            else             { P1.u[2] = lo; P1.u[3] = hi; }
        }
        lsum += ls;

        // V A-fragments + in-register P -> O^T accumulate (no LDS round-trip)
        #pragma unroll
        for (int eg = 0; eg < 4; ++eg) {
            bf16x8 v0 = *(const bf16x8*)&KV[4096 + eg * 1024 + vo0];
            bf16x8 v1 = *(const bf16x8*)&KV[4096 + eg * 1024 + vo1];
            oacc[eg] = __builtin_amdgcn_mfma_f32_16x16x32_bf16(v0, P0.v, oacc[eg], 0, 0, 0);
            oacc[eg] = __builtin_amdgcn_mfma_f32_16x16x32_bf16(v1, P1.v, oacc[eg], 0, 0, 0);
        }
    }

    // final row-sum reduce across the 4 quads (lanes c, c+16, c+32, c+48)
    float linv;
    {
        float l = lsum;
        l += __shfl_xor(l, 16);
        l += __shfl_xor(l, 32);
        linv = 1.0f / l;
    }

    // local branch scores: j = i-2+jj (fp32, natural-log units).
    {
        const int br = tid >> 2;
        const int jj = tid & 3;
        const int i  = i0 + br;
        const int j  = i - 2 + jj;
        float s = -INFINITY;
        if (j >= 0 && j < LQ) {
            const float* qrow = Qbh + (size_t)i * RS;
            const float* krow = Kbh + (size_t)j * RS;
            float acc = 0.f;
            #pragma unroll
            for (int e = 0; e < 64; e += 4) {
                float4 qa = *(const float4*)(qrow + e);
                float4 ka = *(const float4*)(krow + e);
                acc = fmaf(qa.x, ka.x, acc); acc = fmaf(qa.y, ka.y, acc);
                acc = fmaf(qa.z, ka.z, acc); acc = fmaf(qa.w, ka.w, acc);
            }
            s = 0.125f * acc;
        }
        sloc[br][jj] = s;
    }
    __syncthreads();

    // combine global + local, store (O^T: lane holds e=eg*16+g*4+r, q=c)
    {
        const int row = wave * 16 + c;
        const int i   = i0 + row;
        float s0 = sloc[row][0], s1 = sloc[row][1], s2 = sloc[row][2], s3 = sloc[row][3];
        float mx = fmaxf(fmaxf(s0, s1), fmaxf(s2, s3));
        float w0 = expf(s0 - mx), w1 = expf(s1 - mx);
        float w2 = expf(s2 - mx), w3 = expf(s3 - mx);
        float inv = 1.0f / (w0 + w1 + w2 + w3);
        w0 *= inv; w1 *= inv; w2 *= inv; w3 *= inv;
        const float li = linv;
        float* orow = Obh + (size_t)i * RS;
        #pragma unroll
        for (int eg = 0; eg < 4; ++eg) {
            const int e0 = eg * 16 + g * 4;
            float v0 = oacc[eg][0] * li;
            float v1 = oacc[eg][1] * li;
            float v2 = oacc[eg][2] * li;
            float v3 = oacc[eg][3] * li;
            if (w0 > 0.f) {
                float4 vv = *(const float4*)(Vbh + (size_t)(i - 2) * RS + e0);
                v0 = fmaf(w0, vv.x, v0); v1 = fmaf(w0, vv.y, v1);
                v2 = fmaf(w0, vv.z, v2); v3 = fmaf(w0, vv.w, v3);
            }
            if (w1 > 0.f) {
                float4 vv = *(const float4*)(Vbh + (size_t)(i - 1) * RS + e0);
                v0 = fmaf(w1, vv.x, v0); v1 = fmaf(w1, vv.y, v1);
                v2 = fmaf(w1, vv.z, v2); v3 = fmaf(w1, vv.w, v3);
            }
            {
                float4 vv = *(const float4*)(Vbh + (size_t)i * RS + e0);
                v0 = fmaf(w2, vv.x, v0); v1 = fmaf(w2, vv.y, v1);
                v2 = fmaf(w2, vv.z, v2); v3 = fmaf(w2, vv.w, v3);
            }
            if (w3 > 0.f) {
                float4 vv = *(const float4*)(Vbh + (size_t)(i + 1) * RS + e0);
                v0 = fmaf(w3, vv.x, v0); v1 = fmaf(w3, vv.y, v1);
                v2 = fmaf(w3, vv.z, v2); v3 = fmaf(w3, vv.w, v3);
            }
            float4 outv; outv.x = v0; outv.y = v1; outv.z = v2; outv.w = v3;
            *(float4*)(orow + e0) = outv;
        }
    }
}

// ---- fallback (self-contained, no workspace; unchanged) ----
__global__ __launch_bounds__(256) void hybrid_attn_fb(
    const float* __restrict__ Q, const float* __restrict__ K,
    const float* __restrict__ V, float* __restrict__ O)
{
    __shared__ unsigned short Ks[64 * 64];
    __shared__ unsigned short Vt[64 * 64];
    __shared__ unsigned short Ps[4][16 * 64];
    __shared__ float sloc[64][4];

    const int tid  = threadIdx.x;
    const int wave = tid >> 6;
    const int lane = tid & 63;
    const int c    = lane & 15;
    const int g    = lane >> 4;
    const int qt   = blockIdx.x;
    const int bh   = blockIdx.y;
    const int b    = bh >> 3;
    const int h    = bh & 7;
    const int i0   = qt * 64;

    const float* Qbh = Q + (size_t)b * LQ * RS + h * EQ;
    const float* Kbh = K + (size_t)b * LQ * RS + h * EQ;
    const float* Vbh = V + (size_t)b * LQ * RS + h * EQ;
    float*       Obh = O + (size_t)b * LQ * RS + h * EQ;

    bf16x8 qf[2];
    {
        const int iA = i0 + wave * 16 + c;
        const float* qrow = Qbh + (size_t)iA * RS + g * 8;
        #pragma unroll
        for (int f = 0; f < 2; ++f) {
            float4 a  = *(const float4*)(qrow + f * 32);
            float4 bv = *(const float4*)(qrow + f * 32 + 4);
            union { bf16x8 v; unsigned int u[4]; } fr;
            fr.u[0] = pk2(a.x  * SCALE_LOG2E, a.y  * SCALE_LOG2E);
            fr.u[1] = pk2(a.z  * SCALE_LOG2E, a.w  * SCALE_LOG2E);
            fr.u[2] = pk2(bv.x * SCALE_LOG2E, bv.y * SCALE_LOG2E);
            fr.u[3] = pk2(bv.z * SCALE_LOG2E, bv.w * SCALE_LOG2E);
            qf[f] = fr.v;
        }
    }

    int kfo[4][2], vfo[4][2], pfo[2], pso[4][4];
    #pragma unroll
    for (int n = 0; n < 4; ++n)
        #pragma unroll
        for (int f = 0; f < 2; ++f)
            kfo[n][f] = (n * 16 + c) * 64 + ((((f << 2) | g) ^ (c & 7)) << 3);
    #pragma unroll
    for (int eg = 0; eg < 4; ++eg)
        #pragma unroll
        for (int kh = 0; kh < 2; ++kh)
            vfo[eg][kh] = (eg * 16 + c) * 64 + ((((kh << 2) | g) ^ (c & 7)) << 3);
    #pragma unroll
    for (int kh = 0; kh < 2; ++kh)
        pfo[kh] = c * 64 + ((((kh << 2) | g) ^ (c & 7)) << 3);
    #pragma unroll
    for (int r = 0; r < 4; ++r) {
        const int row = g * 4 + r;
        #pragma unroll
        for (int n = 0; n < 4; ++n) {
            const int col = n * 16 + c;
            pso[r][n] = row * 64 + ((((col >> 3) ^ (row & 7)) << 3) | (col & 7));
        }
    }

    f32x4 oacc[4];
    #pragma unroll
    for (int eg = 0; eg < 4; ++eg) oacc[eg] = (f32x4){0.f, 0.f, 0.f, 0.f};
    float l_r[4] = {0.f, 0.f, 0.f, 0.f};

    for (int j0 = 0; j0 < LQ; j0 += BN) {
        __syncthreads();
        #pragma unroll
        for (int it = 0; it < 2; ++it) {
            int t2 = tid + it * 256;
            int jr = t2 >> 3, eo = t2 & 7;
            const float* src = Kbh + (size_t)(j0 + jr) * RS + eo * 8;
            float4 a  = *(const float4*)src;
            float4 bv = *(const float4*)(src + 4);
            u32x4 p;
            p.x = pk2(a.x, a.y);   p.y = pk2(a.z, a.w);
            p.z = pk2(bv.x, bv.y); p.w = pk2(bv.z, bv.w);
            *(u32x4*)&Ks[jr * 64 + ((eo ^ (jr & 7)) << 3)] = p;
        }
        #pragma unroll
        for (int it = 0; it < 2; ++it) {
            int t2 = tid + it * 256;
            int e = t2 & 63, jo = t2 >> 6;
            const float* src = Vbh + (size_t)(j0 + jo * 8) * RS + e;
            float v0 = src[0 * RS], v1 = src[1 * RS], v2 = src[2 * RS], v3 = src[3 * RS];
            float v4 = src[4 * RS], v5 = src[5 * RS], v6 = src[6 * RS], v7 = src[7 * RS];
            u32x4 p;
            p.x = pk2(v0, v1); p.y = pk2(v2, v3);
            p.z = pk2(v4, v5); p.w = pk2(v6, v7);
            *(u32x4*)&Vt[e * 64 + ((jo ^ (e & 7)) << 3)] = p;
        }
        __syncthreads();

        f32x4 sf[4];
        #pragma unroll
        for (int n = 0; n < 4; ++n) {
            bf16x8 k0 = *(const bf16x8*)&Ks[kfo[n][0]];
            bf16x8 k1 = *(const bf16x8*)&Ks[kfo[n][1]];
            f32x4 acc = (f32x4){0.f, 0.f, 0.f, 0.f};
            acc = __builtin_amdgcn_mfma_f32_16x16x32_bf16(qf[0], k0, acc, 0, 0, 0);
            acc = __builtin_amdgcn_mfma_f32_16x16x32_bf16(qf[1], k1, acc, 0, 0, 0);
            sf[n] = acc;
        }
        #pragma unroll
        for (int r = 0; r < 4; ++r) {
            float p0 = fexp2(sf[0][r]);
            float p1 = fexp2(sf[1][r]);
            float p2 = fexp2(sf[2][r]);
            float p3 = fexp2(sf[3][r]);
            l_r[r] += (p0 + p1) + (p2 + p3);
            Ps[wave][pso[r][0]] = (unsigned short)f2bf(p0);
            Ps[wave][pso[r][1]] = (unsigned short)f2bf(p1);
            Ps[wave][pso[r][2]] = (unsigned short)f2bf(p2);
            Ps[wave][pso[r][3]] = (unsigned short)f2bf(p3);
        }
        asm volatile("s_waitcnt lgkmcnt(0)" ::: "memory");

        bf16x8 pf0 = *(const bf16x8*)&Ps[wave][pfo[0]];
        bf16x8 pf1 = *(const bf16x8*)&Ps[wave][pfo[1]];
        #pragma unroll
        for (int eg = 0; eg < 4; ++eg) {
            bf16x8 v0 = *(const bf16x8*)&Vt[vfo[eg][0]];
            bf16x8 v1 = *(const bf16x8*)&Vt[vfo[eg][1]];
            oacc[eg] = __builtin_amdgcn_mfma_f32_16x16x32_bf16(pf0, v0, oacc[eg], 0, 0, 0);
            oacc[eg] = __builtin_amdgcn_mfma_f32_16x16x32_bf16(pf1, v1, oacc[eg], 0, 0, 0);
        }
    }

    #pragma unroll
    for (int r = 0; r < 4; ++r) {
        float l = l_r[r];
        l += __shfl_xor(l, 1);
        l += __shfl_xor(l, 2);
        l += __shfl_xor(l, 4);
        l += __shfl_xor(l, 8);
        l_r[r] = 1.0f / l;
    }

    {
        const int br = tid >> 2;
        const int jj = tid & 3;
        const int i  = i0 + br;
        const int j  = i - 2 + jj;
        float s = -INFINITY;
        if (j >= 0 && j < LQ) {
            const float* qrow = Qbh + (size_t)i * RS;
            const float* krow = Kbh + (size_t)j * RS;
            float acc = 0.f;
            #pragma unroll
            for (int e = 0; e < 64; e += 4) {
                float4 qa = *(const float4*)(qrow + e);
                float4 ka = *(const float4*)(krow + e);
                acc = fmaf(qa.x, ka.x, acc); acc = fmaf(qa.y, ka.y, acc);
                acc = fmaf(qa.z, ka.z, acc); acc = fmaf(qa.w, ka.w, acc);
            }
            s = 0.125f * acc;
        }
        sloc[br][jj] = s;
    }
    __syncthreads();

    #pragma unroll
    for (int r = 0; r < 4; ++r) {
        const int row = wave * 16 + g * 4 + r;
        const int i   = i0 + row;
        float s0 = sloc[row][0], s1 = sloc[row][1], s2 = sloc[row][2], s3 = sloc[row][3];
        float mx = fmaxf(fmaxf(s0, s1), fmaxf(s2, s3));
        float w0 = expf(s0 - mx), w1 = expf(s1 - mx);
        float w2 = expf(s2 - mx), w3 = expf(s3 - mx);
        float inv = 1.0f / (w0 + w1 + w2 + w3);
        w0 *= inv; w1 *= inv; w2 *= inv; w3 *= inv;
        const float li = l_r[r];
        float* orow = Obh + (size_t)i * RS;
        #pragma unroll
        for (int eg = 0; eg < 4; ++eg) {
            const int e = eg * 16 + c;
            float val = oacc[eg][r] * li;
            if (w0 > 0.f) val += w0 * Vbh[(size_t)(i - 2) * RS + e];
            if (w1 > 0.f) val += w1 * Vbh[(size_t)(i - 1) * RS + e];
            if (w2 > 0.f) val += w2 * Vbh[(size_t)(i    ) * RS + e];
            if (w3 > 0.f) val += w3 * Vbh[(size_t)(i + 1) * RS + e];
            orow[e] = val;
        }
    }
}

extern "C" void kernel_launch(void* const* d_in, const int* in_sizes, int n_in,
                              void* d_out, int out_size, void* d_ws, size_t ws_size,
                              hipStream_t stream) {
    (void)in_sizes; (void)n_in; (void)out_size;
    const float* Q = (const float*)d_in[0];
    const float* K = (const float*)d_in[1];
    const float* V = (const float*)d_in[2];
    float* O = (float*)d_out;
    const size_t need = (size_t)2 * IMG_U32 * 4;  // 16 MiB
    if (ws_size >= need) {
        uint32_t* Kimg = (uint32_t*)d_ws;
        uint32_t* Vimg = Kimg + IMG_U32;
        hipLaunchKernelGGL(prepack_kernel, dim3(NTILE, BQ * HQ), dim3(256), 0, stream,
                           K, V, Kimg, Vimg);
        hipLaunchKernelGGL(hybrid_attn_v16, dim3((LQ / BMQ) * BQ * HQ), dim3(256), 0, stream,
                           Q, K, V, Kimg, Vimg, O);
    } else {
        hipLaunchKernelGGL(hybrid_attn_fb, dim3(LQ / 64, BQ * HQ), dim3(256), 0, stream,
                           Q, K, V, O);
    }
}

// Round 12
// 146.573 us; speedup vs baseline: 1.1335x; 1.0147x over previous
//
#include <hip/hip_runtime.h>
#include <hip/hip_bf16.h>
#include <stdint.h>

// HybridAttention: out = (softmax(scale*QK^T) + softmax_local(scale*QK^T)) @ V
// B=4, L=2048, H=8, E=64, fp32 in/out. Local window: j in [i-2, i+1] clamped.
//
// R21: ONE variable vs R16 (69.2us attn, passed) — single-barrier LDS
// double-buffering. Ledger (6 failures incl. single-wave R20): gload_lds
// in flight concurrent with ds_reads = cursed; reg-staged ds_writes are NOT
// (R15/R16 passed). So dbuf via ds_writes is legal: iteration s writes tile
// s+1 into buf p^1 (regs, prefetched last iter) while computing tile s from
// buf p; ONE barrier ends the iteration. Cross-wave check: X.write(p^1)@s
// vs Y.read(p^1)@s+1 -> barrier@s between; vs Y.read(p^1)@s-1 -> barrier
// @s-1 between; X.read(p)@s vs Y.write(p)@s+1 -> barrier@s between. All
// separated. Reg prefetch stays wave-private 1-deep (proven). Removes 32
// barriers and un-serializes staging (was: barrier-staging-barrier with no
// compute overlap). LDS 17->33 KB (KV doubled), still 4 blocks/CU.
// Compute (in-reg P, remapped K rows), prepack v3: R16-VERBATIM.

#define LQ 2048
#define HQ 8
#define EQ 64
#define BQ 4
#define BN 64
#define RS (HQ * EQ)                      // 512 floats between seq positions
#define SCALE_LOG2E 0.18033688011112042f  // 0.125 * log2(e)
#define NTILE (LQ / BN)                   // 32 key-tiles per (b,h)
#define TILE_U32 2048                     // 64x64 bf16 tile = 8 KB = 2048 u32
#define IMG_U32 (BQ * HQ * NTILE * TILE_U32)
#define BMQ 64                            // queries per block

typedef __attribute__((ext_vector_type(8))) short bf16x8;
typedef __attribute__((ext_vector_type(4))) float f32x4;
typedef __attribute__((ext_vector_type(4))) unsigned int u32x4;
typedef __attribute__((ext_vector_type(2))) unsigned int u32x2;

static __device__ __forceinline__ unsigned int f2bf(float f) {
    union { float f; unsigned int u; } c; c.f = f;
    return (c.u + 0x8000u) >> 16;
}
static __device__ __forceinline__ unsigned int pk2(float lo, float hi) {
    union { float f; unsigned int u; } a, b; a.f = lo; b.f = hi;
    return ((a.u + 0x8000u) >> 16) | ((b.u + 0x8000u) & 0xffff0000u);
}
static __device__ __forceinline__ float fexp2(float x) {
    float r;
    asm volatile("v_exp_f32 %0, %1\n\ts_nop 1" : "=v"(r) : "v"(x));
    return r;
}

// ---- pre-pass v3 (R16 verbatim): K position swizzle for remapped reads;
// V path vectorized conflict-free.
__global__ __launch_bounds__(256) void prepack_kernel(
    const float* __restrict__ K, const float* __restrict__ V,
    uint32_t* __restrict__ Kimg, uint32_t* __restrict__ Vimg)
{
    __shared__ float vf[64 * 64];  // [j][chunk-swizzled e] fp32, 16 KB

    const int tid = threadIdx.x;
    const int jc  = blockIdx.x;
    const int bh  = blockIdx.y;
    const int b   = bh >> 3;
    const int h   = bh & 7;
    const int j0  = jc * BN;
    const float* Kbh = K + (size_t)b * LQ * RS + h * EQ;
    const float* Vbh = V + (size_t)b * LQ * RS + h * EQ;
    uint32_t* Kt = Kimg + (size_t)(bh * NTILE + jc) * TILE_U32;
    uint32_t* Vt = Vimg + (size_t)(bh * NTILE + jc) * TILE_U32;

    // K: coalesced fp32 reads -> pk2 -> swizzled u32x4 stores.
    // Position = eo ^ s(jr), s(jr) = (jr&3) | (((jr>>3)&1)<<2)
    #pragma unroll
    for (int it = 0; it < 2; ++it) {
        int t2 = tid + it * 256;
        int jr = t2 >> 3, eo = t2 & 7;
        const float* src = Kbh + (size_t)(j0 + jr) * RS + eo * 8;
        float4 a  = *(const float4*)src;
        float4 bv = *(const float4*)(src + 4);
        u32x4 p;
        p.x = pk2(a.x, a.y);   p.y = pk2(a.z, a.w);
        p.z = pk2(bv.x, bv.y); p.w = pk2(bv.z, bv.w);
        const int s = (jr & 3) | (((jr >> 3) & 1) << 2);
        *(u32x4*)&Kt[jr * 32 + ((eo ^ s) << 2)] = p;
    }

    // V phase 1: coalesced row reads -> swizzled fp32 LDS, all ds_write_b128.
    {
        const int jr = tid >> 2;               // 0..63
        const int s  = (jr & 7) ^ (jr >> 3);   // row swizzle constant
        const float* src = Vbh + (size_t)(j0 + jr) * RS + (tid & 3) * 16;
        #pragma unroll
        for (int q = 0; q < 4; ++q) {
            float4 a = *(const float4*)(src + q * 4);
            const int ec = (tid & 3) * 4 + q;  // e-chunk 0..15
            const int p  = (ec & 8) | ((ec ^ s) & 7);
            *(float4*)&vf[jr * 64 + p * 4] = a;
        }
    }
    __syncthreads();

    // V phase 2: column gather (2-way = free), pk2 pairs, coalesced stores.
    #pragma unroll
    for (int it = 0; it < 2; ++it) {
        const int u   = tid + it * 256;
        const int e   = u >> 3;             // 0..63
        const int jop = u & 7;              // stored (output) chunk position
        const int jo  = jop ^ (e & 7);      // source j-chunk (XOR self-inverse)
        const int ec  = e >> 2;
        float v[8];
        #pragma unroll
        for (int k = 0; k < 8; ++k) {
            const int j = jo * 8 + k;
            const int p = (ec & 8) | ((ec ^ (j & 7) ^ (j >> 3)) & 7);
            v[k] = vf[j * 64 + p * 4 + (e & 3)];
        }
        u32x4 pq;
        pq.x = pk2(v[0], v[1]); pq.y = pk2(v[2], v[3]);
        pq.z = pk2(v[4], v[5]); pq.w = pk2(v[6], v[7]);
        *(u32x4*)&Vt[e * 32 + (jop << 2)] = pq;
    }
}

// ---- main attention kernel: 4 waves, 64 queries/block, 16 queries/wave;
// ---- reg-prefetch + single-barrier LDS double-buffer; in-reg P (R16)
__global__ __launch_bounds__(256, 4) void hybrid_attn_v21(
    const float* __restrict__ Q, const float* __restrict__ K,
    const float* __restrict__ V, const uint32_t* __restrict__ Kimg,
    const uint32_t* __restrict__ Vimg, float* __restrict__ O)
{
    // 2 bufs x (K 4096 + V 4096 ushorts): buf p at [p*8192, p*8192+8192)
    __shared__ unsigned short KV[16384];
    __shared__ float sloc[BMQ][4];

    const int tid  = threadIdx.x;
    const int wave = tid >> 6;
    const int lane = tid & 63;
    const int c    = lane & 15;
    const int g    = lane >> 4;
    // XCD swizzle: xcd = linear_id % 8; 4 bh's per XCD per qt-slice. grid=1024.
    const int id   = blockIdx.x;            // 0..1023
    const int bh   = (id & 7) * 4 + ((id >> 3) & 3);
    const int qt   = id >> 5;               // 0..31
    const int b    = bh >> 3;
    const int h    = bh & 7;
    const int i0   = qt * BMQ;
    const int c7   = c & 7;

    const float* Qbh = Q + (size_t)b * LQ * RS + h * EQ;
    const float* Kbh = K + (size_t)b * LQ * RS + h * EQ;
    const float* Vbh = V + (size_t)b * LQ * RS + h * EQ;
    float*       Obh = O + (size_t)b * LQ * RS + h * EQ;

    // Q as B-operand fragments: one q-tile x 2 e-halves, scale*log2e folded in
    bf16x8 qf[2];
    {
        const int iq = i0 + wave * 16 + c;
        const float* qrow = Qbh + (size_t)iq * RS + g * 8;
        #pragma unroll
        for (int f = 0; f < 2; ++f) {
            float4 a  = *(const float4*)(qrow + f * 32);
            float4 bv = *(const float4*)(qrow + f * 32 + 4);
            union { bf16x8 v; unsigned int u[4]; } fr;
            fr.u[0] = pk2(a.x  * SCALE_LOG2E, a.y  * SCALE_LOG2E);
            fr.u[1] = pk2(a.z  * SCALE_LOG2E, a.w  * SCALE_LOG2E);
            fr.u[2] = pk2(bv.x * SCALE_LOG2E, bv.y * SCALE_LOG2E);
            fr.u[3] = pk2(bv.z * SCALE_LOG2E, bv.w * SCALE_LOG2E);
            qf[f] = fr.v;
        }
    }

    // R16 K-fragment addressing: MFMA n, A-row m reads key
    //   key(n,m) = 8*(m>>2) + (m&3) + {0,4,32,36}[n]
    // so lane (g,c)'s QK^T outputs are exactly its PV B-fragment P values.
    const int rb = ((c >> 2) << 3) + (c & 3);
    const int ss = (c & 3) | (((c >> 2) & 1) << 2);  // lane-constant K swizzle
    int kfo[4][2];
    #pragma unroll
    for (int n = 0; n < 4; ++n) {
        const int off = ((n & 1) << 2) + ((n >> 1) << 5);  // 0,4,32,36
        const int r   = rb + off;
        kfo[n][0] = r * 64 + ((g       ^ ss) << 3);
        kfo[n][1] = r * 64 + (((4 | g) ^ ss) << 3);
    }
    // V A-fragment lane offsets (row = eg*16+c, row&7 = c7)
    const int vo0 = c * 64 + ((g ^ c7) << 3);        // k 0..31 half
    const int vo1 = c * 64 + (((4 | g) ^ c7) << 3);  // k 32..63 half

    // global per-lane source bases — 4-wave x 2KB-contiguous shape (R2-proven)
    const uint32_t* kgb = Kimg + (size_t)bh * (NTILE * TILE_U32) + wave * 512 + lane * 4;
    const uint32_t* vgb = Vimg + (size_t)bh * (NTILE * TILE_U32) + wave * 512 + lane * 4;

    // LDS dest offsets within a buffer (ushort units; lane*8 = 16B per lane)
    const int kdo0 = wave * 1024 + lane * 8;
    const int kdo1 = wave * 1024 + 512 + lane * 8;
    const int vdo0 = 4096 + wave * 1024 + lane * 8;
    const int vdo1 = 4096 + wave * 1024 + 512 + lane * 8;

    f32x4 oacc[4];
    #pragma unroll
    for (int eg = 0; eg < 4; ++eg) oacc[eg] = (f32x4){0.f, 0.f, 0.f, 0.f};
    float lsum = 0.f;

    // prologue: tile0 -> regs -> buf0; prefetch tile1 -> regs; one barrier.
    u32x4 kr0 = *(const u32x4*)kgb;
    u32x4 kr1 = *(const u32x4*)(kgb + 256);
    u32x4 vr0 = *(const u32x4*)vgb;
    u32x4 vr1 = *(const u32x4*)(vgb + 256);
    *(u32x4*)&KV[kdo0] = kr0;
    *(u32x4*)&KV[kdo1] = kr1;
    *(u32x4*)&KV[vdo0] = vr0;
    *(u32x4*)&KV[vdo1] = vr1;
    {
        const uint32_t* kg = kgb + TILE_U32;
        const uint32_t* vg = vgb + TILE_U32;
        kr0 = *(const u32x4*)kg;
        kr1 = *(const u32x4*)(kg + 256);
        vr0 = *(const u32x4*)vg;
        vr1 = *(const u32x4*)(vg + 256);
    }
    __syncthreads();   // tile0 visible to all waves

    for (int jc = 0; jc < NTILE; ++jc) {
        const int p  = jc & 1;
        const int rb_ = p * 8192;        // read buffer base (tile jc)
        // stage tile jc+1 (regs) into the OTHER buffer; overlaps compute.
        if (jc + 1 < NTILE) {
            const int wb = (p ^ 1) * 8192;
            *(u32x4*)&KV[wb + kdo0] = kr0;
            *(u32x4*)&KV[wb + kdo1] = kr1;
            *(u32x4*)&KV[wb + vdo0] = vr0;
            *(u32x4*)&KV[wb + vdo1] = vr1;
            // prefetch tile jc+2 into regs (wave-private, 1-deep, proven)
            if (jc + 2 < NTILE) {
                const uint32_t* kg = kgb + (size_t)(jc + 2) * TILE_U32;
                const uint32_t* vg = vgb + (size_t)(jc + 2) * TILE_U32;
                kr0 = *(const u32x4*)kg;
                kr1 = *(const u32x4*)(kg + 256);
                vr0 = *(const u32x4*)vg;
                vr1 = *(const u32x4*)(vg + 256);
            }
        }

        // K A-fragments (remapped rows) from the READ buffer
        bf16x8 kfr[4][2];
        #pragma unroll
        for (int n = 0; n < 4; ++n) {
            kfr[n][0] = *(const bf16x8*)&KV[rb_ + kfo[n][0]];
            kfr[n][1] = *(const bf16x8*)&KV[rb_ + kfo[n][1]];
        }

        // S^T = K*Q^T; sf[n][r] = S[q=c][k = 8g + r + {0,4,32,36}[n]]
        f32x4 sf[4];
        #pragma unroll
        for (int n = 0; n < 4; ++n) {
            f32x4 acc = (f32x4){0.f, 0.f, 0.f, 0.f};
            acc = __builtin_amdgcn_mfma_f32_16x16x32_bf16(kfr[n][0], qf[0], acc, 0, 0, 0);
            acc = __builtin_amdgcn_mfma_f32_16x16x32_bf16(kfr[n][1], qf[1], acc, 0, 0, 0);
            sf[n] = acc;
        }

        // p = exp2(s); pack IN REGISTER into the PV B-fragments.
        union { bf16x8 v; unsigned int u[4]; } P0, P1;
        float ls = 0.f;
        #pragma unroll
        for (int n = 0; n < 4; ++n) {
            float p0 = fexp2(sf[n][0]);
            float p1 = fexp2(sf[n][1]);
            float p2 = fexp2(sf[n][2]);
            float p3 = fexp2(sf[n][3]);
            ls += (p0 + p1) + (p2 + p3);
            const unsigned int lo = pk2(p0, p1);
            const unsigned int hi = pk2(p2, p3);
            if (n == 0)      { P0.u[0] = lo; P0.u[1] = hi; }
            else if (n == 1) { P0.u[2] = lo; P0.u[3] = hi; }
            else if (n == 2) { P1.u[0] = lo; P1.u[1] = hi; }
            else             { P1.u[2] = lo; P1.u[3] = hi; }
        }
        lsum += ls;

        // V A-fragments + in-register P -> O^T accumulate
        #pragma unroll
        for (int eg = 0; eg < 4; ++eg) {
            bf16x8 v0 = *(const bf16x8*)&KV[rb_ + 4096 + eg * 1024 + vo0];
            bf16x8 v1 = *(const bf16x8*)&KV[rb_ + 4096 + eg * 1024 + vo1];
            oacc[eg] = __builtin_amdgcn_mfma_f32_16x16x32_bf16(v0, P0.v, oacc[eg], 0, 0, 0);
            oacc[eg] = __builtin_amdgcn_mfma_f32_16x16x32_bf16(v1, P1.v, oacc[eg], 0, 0, 0);
        }

        // ONE barrier per iteration: makes this iter's writes to buf p^1
        // visible for iter jc+1, and guarantees all waves' reads of buf p
        // are done before iter jc+1 overwrites it.
        __syncthreads();
    }

    // final row-sum reduce across the 4 quads (lanes c, c+16, c+32, c+48)
    float linv;
    {
        float l = lsum;
        l += __shfl_xor(l, 16);
        l += __shfl_xor(l, 32);
        linv = 1.0f / l;
    }

    // local branch scores: j = i-2+jj (fp32, natural-log units).
    {
        const int br = tid >> 2;
        const int jj = tid & 3;
        const int i  = i0 + br;
        const int j  = i - 2 + jj;
        float s = -INFINITY;
        if (j >= 0 && j < LQ) {
            const float* qrow = Qbh + (size_t)i * RS;
            const float* krow = Kbh + (size_t)j * RS;
            float acc = 0.f;
            #pragma unroll
            for (int e = 0; e < 64; e += 4) {
                float4 qa = *(const float4*)(qrow + e);
                float4 ka = *(const float4*)(krow + e);
                acc = fmaf(qa.x, ka.x, acc); acc = fmaf(qa.y, ka.y, acc);
                acc = fmaf(qa.z, ka.z, acc); acc = fmaf(qa.w, ka.w, acc);
            }
            s = 0.125f * acc;
        }
        sloc[br][jj] = s;
    }
    __syncthreads();

    // combine global + local, store (O^T: lane holds e=eg*16+g*4+r, q=c)
    {
        const int row = wave * 16 + c;
        const int i   = i0 + row;
        float s0 = sloc[row][0], s1 = sloc[row][1], s2 = sloc[row][2], s3 = sloc[row][3];
        float mx = fmaxf(fmaxf(s0, s1), fmaxf(s2, s3));
        float w0 = expf(s0 - mx), w1 = expf(s1 - mx);
        float w2 = expf(s2 - mx), w3 = expf(s3 - mx);
        float inv = 1.0f / (w0 + w1 + w2 + w3);
        w0 *= inv; w1 *= inv; w2 *= inv; w3 *= inv;
        const float li = linv;
        float* orow = Obh + (size_t)i * RS;
        #pragma unroll
        for (int eg = 0; eg < 4; ++eg) {
            const int e0 = eg * 16 + g * 4;
            float v0 = oacc[eg][0] * li;
            float v1 = oacc[eg][1] * li;
            float v2 = oacc[eg][2] * li;
            float v3 = oacc[eg][3] * li;
            if (w0 > 0.f) {
                float4 vv = *(const float4*)(Vbh + (size_t)(i - 2) * RS + e0);
                v0 = fmaf(w0, vv.x, v0); v1 = fmaf(w0, vv.y, v1);
                v2 = fmaf(w0, vv.z, v2); v3 = fmaf(w0, vv.w, v3);
            }
            if (w1 > 0.f) {
                float4 vv = *(const float4*)(Vbh + (size_t)(i - 1) * RS + e0);
                v0 = fmaf(w1, vv.x, v0); v1 = fmaf(w1, vv.y, v1);
                v2 = fmaf(w1, vv.z, v2); v3 = fmaf(w1, vv.w, v3);
            }
            {
                float4 vv = *(const float4*)(Vbh + (size_t)i * RS + e0);
                v0 = fmaf(w2, vv.x, v0); v1 = fmaf(w2, vv.y, v1);
                v2 = fmaf(w2, vv.z, v2); v3 = fmaf(w2, vv.w, v3);
            }
            if (w3 > 0.f) {
                float4 vv = *(const float4*)(Vbh + (size_t)(i + 1) * RS + e0);
                v0 = fmaf(w3, vv.x, v0); v1 = fmaf(w3, vv.y, v1);
                v2 = fmaf(w3, vv.z, v2); v3 = fmaf(w3, vv.w, v3);
            }
            float4 outv; outv.x = v0; outv.y = v1; outv.z = v2; outv.w = v3;
            *(float4*)(orow + e0) = outv;
        }
    }
}

// ---- fallback (self-contained, no workspace; unchanged) ----
__global__ __launch_bounds__(256) void hybrid_attn_fb(
    const float* __restrict__ Q, const float* __restrict__ K,
    const float* __restrict__ V, float* __restrict__ O)
{
    __shared__ unsigned short Ks[64 * 64];
    __shared__ unsigned short Vt[64 * 64];
    __shared__ unsigned short Ps[4][16 * 64];
    __shared__ float sloc[64][4];

    const int tid  = threadIdx.x;
    const int wave = tid >> 6;
    const int lane = tid & 63;
    const int c    = lane & 15;
    const int g    = lane >> 4;
    const int qt   = blockIdx.x;
    const int bh   = blockIdx.y;
    const int b    = bh >> 3;
    const int h    = bh & 7;
    const int i0   = qt * 64;

    const float* Qbh = Q + (size_t)b * LQ * RS + h * EQ;
    const float* Kbh = K + (size_t)b * LQ * RS + h * EQ;
    const float* Vbh = V + (size_t)b * LQ * RS + h * EQ;
    float*       Obh = O + (size_t)b * LQ * RS + h * EQ;

    bf16x8 qf[2];
    {
        const int iA = i0 + wave * 16 + c;
        const float* qrow = Qbh + (size_t)iA * RS + g * 8;
        #pragma unroll
        for (int f = 0; f < 2; ++f) {
            float4 a  = *(const float4*)(qrow + f * 32);
            float4 bv = *(const float4*)(qrow + f * 32 + 4);
            union { bf16x8 v; unsigned int u[4]; } fr;
            fr.u[0] = pk2(a.x  * SCALE_LOG2E, a.y  * SCALE_LOG2E);
            fr.u[1] = pk2(a.z  * SCALE_LOG2E, a.w  * SCALE_LOG2E);
            fr.u[2] = pk2(bv.x * SCALE_LOG2E, bv.y * SCALE_LOG2E);
            fr.u[3] = pk2(bv.z * SCALE_LOG2E, bv.w * SCALE_LOG2E);
            qf[f] = fr.v;
        }
    }

    int kfo[4][2], vfo[4][2], pfo[2], pso[4][4];
    #pragma unroll
    for (int n = 0; n < 4; ++n)
        #pragma unroll
        for (int f = 0; f < 2; ++f)
            kfo[n][f] = (n * 16 + c) * 64 + ((((f << 2) | g) ^ (c & 7)) << 3);
    #pragma unroll
    for (int eg = 0; eg < 4; ++eg)
        #pragma unroll
        for (int kh = 0; kh < 2; ++kh)
            vfo[eg][kh] = (eg * 16 + c) * 64 + ((((kh << 2) | g) ^ (c & 7)) << 3);
    #pragma unroll
    for (int kh = 0; kh < 2; ++kh)
        pfo[kh] = c * 64 + ((((kh << 2) | g) ^ (c & 7)) << 3);
    #pragma unroll
    for (int r = 0; r < 4; ++r) {
        const int row = g * 4 + r;
        #pragma unroll
        for (int n = 0; n < 4; ++n) {
            const int col = n * 16 + c;
            pso[r][n] = row * 64 + ((((col >> 3) ^ (row & 7)) << 3) | (col & 7));
        }
    }

    f32x4 oacc[4];
    #pragma unroll
    for (int eg = 0; eg < 4; ++eg) oacc[eg] = (f32x4){0.f, 0.f, 0.f, 0.f};
    float l_r[4] = {0.f, 0.f, 0.f, 0.f};

    for (int j0 = 0; j0 < LQ; j0 += BN) {
        __syncthreads();
        #pragma unroll
        for (int it = 0; it < 2; ++it) {
            int t2 = tid + it * 256;
            int jr = t2 >> 3, eo = t2 & 7;
            const float* src = Kbh + (size_t)(j0 + jr) * RS + eo * 8;
            float4 a  = *(const float4*)src;
            float4 bv = *(const float4*)(src + 4);
            u32x4 p;
            p.x = pk2(a.x, a.y);   p.y = pk2(a.z, a.w);
            p.z = pk2(bv.x, bv.y); p.w = pk2(bv.z, bv.w);
            *(u32x4*)&Ks[jr * 64 + ((eo ^ (jr & 7)) << 3)] = p;
        }
        #pragma unroll
        for (int it = 0; it < 2; ++it) {
            int t2 = tid + it * 256;
            int e = t2 & 63, jo = t2 >> 6;
            const float* src = Vbh + (size_t)(j0 + jo * 8) * RS + e;
            float v0 = src[0 * RS], v1 = src[1 * RS], v2 = src[2 * RS], v3 = src[3 * RS];
            float v4 = src[4 * RS], v5 = src[5 * RS], v6 = src[6 * RS], v7 = src[7 * RS];
            u32x4 p;
            p.x = pk2(v0, v1); p.y = pk2(v2, v3);
            p.z = pk2(v4, v5); p.w = pk2(v6, v7);
            *(u32x4*)&Vt[e * 64 + ((jo ^ (e & 7)) << 3)] = p;
        }
        __syncthreads();

        f32x4 sf[4];
        #pragma unroll
        for (int n = 0; n < 4; ++n) {
            bf16x8 k0 = *(const bf16x8*)&Ks[kfo[n][0]];
            bf16x8 k1 = *(const bf16x8*)&Ks[kfo[n][1]];
            f32x4 acc = (f32x4){0.f, 0.f, 0.f, 0.f};
            acc = __builtin_amdgcn_mfma_f32_16x16x32_bf16(qf[0], k0, acc, 0, 0, 0);
            acc = __builtin_amdgcn_mfma_f32_16x16x32_bf16(qf[1], k1, acc, 0, 0, 0);
            sf[n] = acc;
        }
        #pragma unroll
        for (int r = 0; r < 4; ++r) {
            float p0 = fexp2(sf[0][r]);
            float p1 = fexp2(sf[1][r]);
            float p2 = fexp2(sf[2][r]);
            float p3 = fexp2(sf[3][r]);
            l_r[r] += (p0 + p1) + (p2 + p3);
            Ps[wave][pso[r][0]] = (unsigned short)f2bf(p0);
            Ps[wave][pso[r][1]] = (unsigned short)f2bf(p1);
            Ps[wave][pso[r][2]] = (unsigned short)f2bf(p2);
            Ps[wave][pso[r][3]] = (unsigned short)f2bf(p3);
        }
        asm volatile("s_waitcnt lgkmcnt(0)" ::: "memory");

        bf16x8 pf0 = *(const bf16x8*)&Ps[wave][pfo[0]];
        bf16x8 pf1 = *(const bf16x8*)&Ps[wave][pfo[1]];
        #pragma unroll
        for (int eg = 0; eg < 4; ++eg) {
            bf16x8 v0 = *(const bf16x8*)&Vt[vfo[eg][0]];
            bf16x8 v1 = *(const bf16x8*)&Vt[vfo[eg][1]];
            oacc[eg] = __builtin_amdgcn_mfma_f32_16x16x32_bf16(pf0, v0, oacc[eg], 0, 0, 0);
            oacc[eg] = __builtin_amdgcn_mfma_f32_16x16x32_bf16(pf1, v1, oacc[eg], 0, 0, 0);
        }
    }

    #pragma unroll
    for (int r = 0; r < 4; ++r) {
        float l = l_r[r];
        l += __shfl_xor(l, 1);
        l += __shfl_xor(l, 2);
        l += __shfl_xor(l, 4);
        l += __shfl_xor(l, 8);
        l_r[r] = 1.0f / l;
    }

    {
        const int br = tid >> 2;
        const int jj = tid & 3;
        const int i  = i0 + br;
        const int j  = i - 2 + jj;
        float s = -INFINITY;
        if (j >= 0 && j < LQ) {
            const float* qrow = Qbh + (size_t)i * RS;
            const float* krow = Kbh + (size_t)j * RS;
            float acc = 0.f;
            #pragma unroll
            for (int e = 0; e < 64; e += 4) {
                float4 qa = *(const float4*)(qrow + e);
                float4 ka = *(const float4*)(krow + e);
                acc = fmaf(qa.x, ka.x, acc); acc = fmaf(qa.y, ka.y, acc);
                acc = fmaf(qa.z, ka.z, acc); acc = fmaf(qa.w, ka.w, acc);
            }
            s = 0.125f * acc;
        }
        sloc[br][jj] = s;
    }
    __syncthreads();

    #pragma unroll
    for (int r = 0; r < 4; ++r) {
        const int row = wave * 16 + g * 4 + r;
        const int i   = i0 + row;
        float s0 = sloc[row][0], s1 = sloc[row][1], s2 = sloc[row][2], s3 = sloc[row][3];
        float mx = fmaxf(fmaxf(s0, s1), fmaxf(s2, s3));
        float w0 = expf(s0 - mx), w1 = expf(s1 - mx);
        float w2 = expf(s2 - mx), w3 = expf(s3 - mx);
        float inv = 1.0f / (w0 + w1 + w2 + w3);
        w0 *= inv; w1 *= inv; w2 *= inv; w3 *= inv;
        const float li = l_r[r];
        float* orow = Obh + (size_t)i * RS;
        #pragma unroll
        for (int eg = 0; eg < 4; ++eg) {
            const int e = eg * 16 + c;
            float val = oacc[eg][r] * li;
            if (w0 > 0.f) val += w0 * Vbh[(size_t)(i - 2) * RS + e];
            if (w1 > 0.f) val += w1 * Vbh[(size_t)(i - 1) * RS + e];
            if (w2 > 0.f) val += w2 * Vbh[(size_t)(i    ) * RS + e];
            if (w3 > 0.f) val += w3 * Vbh[(size_t)(i + 1) * RS + e];
            orow[e] = val;
        }
    }
}

extern "C" void kernel_launch(void* const* d_in, const int* in_sizes, int n_in,
                              void* d_out, int out_size, void* d_ws, size_t ws_size,
                              hipStream_t stream) {
    (void)in_sizes; (void)n_in; (void)out_size;
    const float* Q = (const float*)d_in[0];
    const float* K = (const float*)d_in[1];
    const float* V = (const float*)d_in[2];
    float* O = (float*)d_out;
    const size_t need = (size_t)2 * IMG_U32 * 4;  // 16 MiB
    if (ws_size >= need) {
        uint32_t* Kimg = (uint32_t*)d_ws;
        uint32_t* Vimg = Kimg + IMG_U32;
        hipLaunchKernelGGL(prepack_kernel, dim3(NTILE, BQ * HQ), dim3(256), 0, stream,
                           K, V, Kimg, Vimg);
        hipLaunchKernelGGL(hybrid_attn_v21, dim3((LQ / BMQ) * BQ * HQ), dim3(256), 0, stream,
                           Q, K, V, Kimg, Vimg, O);
    } else {
        hipLaunchKernelGGL(hybrid_attn_fb, dim3(LQ / 64, BQ * HQ), dim3(256), 0, stream,
                           Q, K, V, O);
    }
}